// Round 2
// baseline (255.386 us; speedup 1.0000x reference)
//
#include <hip/hip_runtime.h>
#include <math.h>

// Problem constants
#define B_   64
#define S_   64
#define W_   12
#define V_   32000
#define SYM_ 128
#define HID_ 256
#define E_   64
#define R_   32

__device__ __forceinline__ float fast_tanh(float x) {
  // tanh(x) = 1 - 2/(e^{2x}+1); v_exp + v_rcp, ~1e-7 abs error, saturates correctly
  float e = __expf(2.0f * x);
  return 1.0f - 2.0f * __builtin_amdgcn_rcpf(e + 1.0f);
}

// wave-uniform broadcast from lane `lane` (runtime-uniform index, like k_scan)
__device__ __forceinline__ float bcast(float v, int lane) {
  return __int_as_float(__builtin_amdgcn_readlane(__float_as_int(v), lane));
}

// ---------------------------------------------------------------------------
// K1: embedding sums for story (rows 0..4095) and query (rows 4096..4159)
// ---------------------------------------------------------------------------
__global__ __launch_bounds__(128) void k_embed(
    const int* __restrict__ story, const int* __restrict__ query,
    const float* __restrict__ we, const float* __restrict__ pe,
    float* __restrict__ X) {
  int row = blockIdx.x;
  int e = threadIdx.x;
  const int* idx = (row < 4096) ? story + row * W_ : query + (row - 4096) * W_;
  float acc = 0.f;
#pragma unroll
  for (int w = 0; w < W_; ++w)
    acc = fmaf(we[(long)idx[w] * SYM_ + e], pe[w * SYM_ + e], acc);
  X[row * SYM_ + e] = acc;
}

// ---------------------------------------------------------------------------
// K2 v9: ZERO-LDS MLP via v_readlane broadcasts.
// Block = 1 wave (64 thr), 8 rows, 1 head; grid 2600. No LDS, no barriers.
// X distributed in registers: lane l holds X[r][2l..2l+1]; layer-1 broadcasts
// X[r][k] via v_readlane (runtime-uniform index -> SGPR -> fmac with SGPR
// operand). H never leaves registers: layer-2 broadcasts h[r][4g+j] from lane
// g the same way. Removes ~770 broadcast ds_read_b128/wave (16B unique data
// per full LDS-pipe slot) that throttled the shared LDS return path, and all
// staging/fences. W1/W2 stream per-lane from L2 as before.
// ---------------------------------------------------------------------------
__global__ __launch_bounds__(64) void k_mlp(
    const float* __restrict__ X,
    const float* __restrict__ ueW1, const float* __restrict__ ueb1,
    const float* __restrict__ ueW2, const float* __restrict__ ueb2,
    const float* __restrict__ urW1, const float* __restrict__ urb1,
    const float* __restrict__ urW2, const float* __restrict__ urb2,
    const float* __restrict__ ieW1, const float* __restrict__ ieb1,
    const float* __restrict__ ieW2, const float* __restrict__ ieb2,
    const float* __restrict__ irW1, const float* __restrict__ irb1,
    const float* __restrict__ irW2, const float* __restrict__ irb2,
    float* __restrict__ oE0, float* __restrict__ oE1,
    float* __restrict__ oR0, float* __restrict__ oR1, float* __restrict__ oR2) {
  int h = blockIdx.x % 5;
  int rowbase = (blockIdx.x / 5) * 8;
  bool isQ = (rowbase >= 4096);
  bool isE = (h < 2);
  const float* W1 = isE ? (isQ ? ieW1 : ueW1) + h * (SYM_ * HID_)
                        : (isQ ? irW1 : urW1) + (h - 2) * (SYM_ * HID_);
  const float* b1 = isE ? (isQ ? ieb1 : ueb1) + h * HID_
                        : (isQ ? irb1 : urb1) + (h - 2) * HID_;
  const float* W2 = isE ? (isQ ? ieW2 : ueW2) + h * (HID_ * E_)
                        : (isQ ? irW2 : urW2) + (h - 2) * (HID_ * R_);
  const float* b2 = isE ? (isQ ? ieb2 : ueb2) + h * E_
                        : (isQ ? irb2 : urb2) + (h - 2) * R_;
  float* out = (h == 0) ? oE0 : (h == 1) ? oE1 : (h == 2) ? oR0 : (h == 3) ? oR1 : oR2;

  int l = threadIdx.x;  // lane 0..63

  // X in registers, k-distributed: lane l holds X[r][2l], X[r][2l+1].
  // Coalesced: 64 lanes x 8B = one 512B contiguous row.
  float2 xreg[8];
#pragma unroll
  for (int r = 0; r < 8; ++r)
    xreg[r] = *(const float2*)(X + (long)(rowbase + r) * SYM_ + 2 * l);

  // layer 1: a[r][q] = sum_k X[r][k] * W1[k][4l+q]
  float a[8][4];
#pragma unroll
  for (int r = 0; r < 8; ++r)
#pragma unroll
    for (int q = 0; q < 4; ++q) a[r][q] = 0.f;

  const float* W1p = W1 + 4 * l;
#pragma unroll 2
  for (int kg = 0; kg < 32; ++kg) {
    float4 w0 = *(const float4*)(W1p + (long)(4 * kg + 0) * HID_);
    float4 w1 = *(const float4*)(W1p + (long)(4 * kg + 1) * HID_);
    float4 w2 = *(const float4*)(W1p + (long)(4 * kg + 2) * HID_);
    float4 w3 = *(const float4*)(W1p + (long)(4 * kg + 3) * HID_);
    int la = 2 * kg, lb = 2 * kg + 1;  // owner lanes of k=4kg..4kg+3
#pragma unroll
    for (int r = 0; r < 8; ++r) {
      float x0 = bcast(xreg[r].x, la);   // X[r][4kg+0]
      float x1 = bcast(xreg[r].y, la);   // X[r][4kg+1]
      float x2 = bcast(xreg[r].x, lb);   // X[r][4kg+2]
      float x3 = bcast(xreg[r].y, lb);   // X[r][4kg+3]
      a[r][0] = fmaf(x0, w0.x, a[r][0]);
      a[r][1] = fmaf(x0, w0.y, a[r][1]);
      a[r][2] = fmaf(x0, w0.z, a[r][2]);
      a[r][3] = fmaf(x0, w0.w, a[r][3]);
      a[r][0] = fmaf(x1, w1.x, a[r][0]);
      a[r][1] = fmaf(x1, w1.y, a[r][1]);
      a[r][2] = fmaf(x1, w1.z, a[r][2]);
      a[r][3] = fmaf(x1, w1.w, a[r][3]);
      a[r][0] = fmaf(x2, w2.x, a[r][0]);
      a[r][1] = fmaf(x2, w2.y, a[r][1]);
      a[r][2] = fmaf(x2, w2.z, a[r][2]);
      a[r][3] = fmaf(x2, w2.w, a[r][3]);
      a[r][0] = fmaf(x3, w3.x, a[r][0]);
      a[r][1] = fmaf(x3, w3.y, a[r][1]);
      a[r][2] = fmaf(x3, w3.z, a[r][2]);
      a[r][3] = fmaf(x3, w3.w, a[r][3]);
    }
  }

  // bias + tanh; h stays in registers (lane l holds h[r][4l..4l+3])
  {
    float4 b1v = *(const float4*)(b1 + 4 * l);
#pragma unroll
    for (int r = 0; r < 8; ++r) {
      a[r][0] = fast_tanh(a[r][0] + b1v.x);
      a[r][1] = fast_tanh(a[r][1] + b1v.y);
      a[r][2] = fast_tanh(a[r][2] + b1v.z);
      a[r][3] = fast_tanh(a[r][3] + b1v.w);
    }
  }

  // layer 2: out[r][c] = sum_hid h[r][hid] * W2[hid][c]; hid=4g+j owned by lane g
  if (isE) {
    float acc[8];
#pragma unroll
    for (int r = 0; r < 8; ++r) acc[r] = 0.f;
#pragma unroll 2
    for (int g = 0; g < 64; ++g) {
      float w0 = W2[(long)(4 * g + 0) * E_ + l];
      float w1 = W2[(long)(4 * g + 1) * E_ + l];
      float w2 = W2[(long)(4 * g + 2) * E_ + l];
      float w3 = W2[(long)(4 * g + 3) * E_ + l];
#pragma unroll
      for (int r = 0; r < 8; ++r) {
        float h0 = bcast(a[r][0], g);
        float h1 = bcast(a[r][1], g);
        float h2 = bcast(a[r][2], g);
        float h3 = bcast(a[r][3], g);
        acc[r] = fmaf(h0, w0, fmaf(h1, w1, fmaf(h2, w2, fmaf(h3, w3, acc[r]))));
      }
    }
    float bb = b2[l];
#pragma unroll
    for (int r = 0; r < 8; ++r)
      out[(long)(rowbase + r) * E_ + l] = acc[r] + bb;
  } else {
    // R head: halves duplicate cols (readlane index must be wave-uniform)
    int lc = l & 31;
    float acc[8];
#pragma unroll
    for (int r = 0; r < 8; ++r) acc[r] = 0.f;
#pragma unroll 2
    for (int g = 0; g < 64; ++g) {
      float w0 = W2[(long)(4 * g + 0) * R_ + lc];
      float w1 = W2[(long)(4 * g + 1) * R_ + lc];
      float w2 = W2[(long)(4 * g + 2) * R_ + lc];
      float w3 = W2[(long)(4 * g + 3) * R_ + lc];
#pragma unroll
      for (int r = 0; r < 8; ++r) {
        float h0 = bcast(a[r][0], g);
        float h1 = bcast(a[r][1], g);
        float h2 = bcast(a[r][2], g);
        float h3 = bcast(a[r][3], g);
        acc[r] = fmaf(h0, w0, fmaf(h1, w1, fmaf(h2, w2, fmaf(h3, w3, acc[r]))));
      }
    }
    if (l < 32) {
      float bb = b2[lc];
#pragma unroll
      for (int r = 0; r < 8; ++r)
        out[(long)(rowbase + r) * R_ + lc] = acc[r] + bb;
    }
  }
}

// ---------------------------------------------------------------------------
// K_gram v2: writes TRANSPOSED Wt[b][m][j][s]  (unchanged)
// ---------------------------------------------------------------------------
__global__ __launch_bounds__(256) void k_gram(
    const float* __restrict__ e1, const float* __restrict__ e2,
    const float* __restrict__ r1, const float* __restrict__ r2,
    const float* __restrict__ r3, float* __restrict__ Wt) {
  int b = blockIdx.x / 9, m = blockIdx.x % 9;
  const float* sE = ((m < 6) ? e1 : e2) + (long)b * S_ * E_;
  const float* jE = ((m == 2 || m == 5 || m == 8) ? e2 : e1) + (long)b * S_ * E_;
  int sk = m / 3, jk = m % 3;
  const float* sR = ((sk == 0) ? r1 : (sk == 1) ? r2 : r3) + (long)b * S_ * R_;
  const float* jR = ((jk == 0) ? r1 : (jk == 1) ? r2 : r3) + (long)b * S_ * R_;

  __shared__ float Es[64][68], Ej[64][68], Rs[64][36], Rj[64][36];
  int tid = threadIdx.x;
  for (int i = tid; i < 1024; i += 256) {
    int row = i >> 4, c = i & 15;
    *(float4*)&Es[row][4 * c] = *(const float4*)(sE + row * 64 + 4 * c);
    *(float4*)&Ej[row][4 * c] = *(const float4*)(jE + row * 64 + 4 * c);
  }
  for (int i = tid; i < 512; i += 256) {
    int row = i >> 3, c = i & 7;
    *(float4*)&Rs[row][4 * c] = *(const float4*)(sR + row * 32 + 4 * c);
    *(float4*)&Rj[row][4 * c] = *(const float4*)(jR + row * 32 + 4 * c);
  }
  __syncthreads();

  int s0 = (tid & 15) * 4, j0 = (tid >> 4) * 4;
  float ed[4][4] = {}, rd[4][4] = {};  // [s][j]
#pragma unroll 4
  for (int k = 0; k < 16; ++k) {
    float4 es[4], ej[4];
#pragma unroll
    for (int i = 0; i < 4; ++i) {
      es[i] = *(const float4*)&Es[s0 + i][4 * k];
      ej[i] = *(const float4*)&Ej[j0 + i][4 * k];
    }
#pragma unroll
    for (int i = 0; i < 4; ++i)
#pragma unroll
      for (int j = 0; j < 4; ++j)
        ed[i][j] = fmaf(es[i].x, ej[j].x, fmaf(es[i].y, ej[j].y,
                   fmaf(es[i].z, ej[j].z, fmaf(es[i].w, ej[j].w, ed[i][j]))));
  }
#pragma unroll 4
  for (int k = 0; k < 8; ++k) {
    float4 rs[4], rj[4];
#pragma unroll
    for (int i = 0; i < 4; ++i) {
      rs[i] = *(const float4*)&Rs[s0 + i][4 * k];
      rj[i] = *(const float4*)&Rj[j0 + i][4 * k];
    }
#pragma unroll
    for (int i = 0; i < 4; ++i)
#pragma unroll
      for (int j = 0; j < 4; ++j)
        rd[i][j] = fmaf(rs[i].x, rj[j].x, fmaf(rs[i].y, rj[j].y,
                   fmaf(rs[i].z, rj[j].z, fmaf(rs[i].w, rj[j].w, rd[i][j]))));
  }
  float* wout = Wt + (long)(b * 9 + m) * 4096;
#pragma unroll
  for (int jj = 0; jj < 4; ++jj) {
    float4 o4 = make_float4(ed[0][jj] * rd[0][jj], ed[1][jj] * rd[1][jj],
                            ed[2][jj] * rd[2][jj], ed[3][jj] * rd[3][jj]);
    *(float4*)(wout + (j0 + jj) * 64 + s0) = o4;  // [j][s]
  }
}

// ---------------------------------------------------------------------------
// K_scan v6 (unchanged): outer-product recurrence, LDS-staged Wt.
// ---------------------------------------------------------------------------
__global__ __launch_bounds__(256) void k_scan(
    const float* __restrict__ e1g, const float* __restrict__ e2g,
    const float* __restrict__ Wt, float4* __restrict__ acd) {
  __shared__ float WtL[9 * 512];
  int b = blockIdx.x & 63;
  int g = blockIdx.x >> 6;
  int tid = threadIdx.x;
  int wv = tid >> 6;
  int lane = tid & 63;             // = s
  int f0 = g * 8 + wv * 2;
  int f1 = f0 + 1;
  const float* Wb = Wt + (long)b * 9 * 4096;
  long eoff = ((long)b * 64 + lane) * 64;
  float e1x = e1g[eoff + f0], e1y = e1g[eoff + f1];
  float e2x = e2g[eoff + f0], e2y = e2g[eoff + f1];

  float pW0 = 0.f, pM0 = 0.f, pB0 = 0.f;
  float pW1 = 0.f, pM1 = 0.f, pB1 = 0.f;
  float ca0 = e2x, cc0 = 0.f, cd0 = e1x;
  float ca1 = e2y, cc1 = 0.f, cd1 = e1y;
  float ka0 = 0.f, kc0 = 0.f, kd0 = 0.f;
  float ka1 = 0.f, kc1 = 0.f, kd1 = 0.f;

  for (int jc = 0; jc < 8; ++jc) {
    __syncthreads();
    for (int i = tid; i < 1152; i += 256) {
      int m = i >> 7;
      int off = (i & 127) * 4;
      *(float4*)&WtL[m * 512 + off] = *(const float4*)(Wb + m * 4096 + jc * 512 + off);
    }
    __syncthreads();
#pragma unroll
    for (int jj = 0; jj < 8; ++jj) {
      int j = jc * 8 + jj;
      float wa = WtL[0 * 512 + jj * 64 + lane];
      float wc = WtL[1 * 512 + jj * 64 + lane];
      float wd = WtL[2 * 512 + jj * 64 + lane];
      float ma = WtL[3 * 512 + jj * 64 + lane];
      float mc = WtL[4 * 512 + jj * 64 + lane];
      float md = WtL[5 * 512 + jj * 64 + lane];
      float ba = WtL[6 * 512 + jj * 64 + lane];
      float bc = WtL[7 * 512 + jj * 64 + lane];
      float bd = WtL[8 * 512 + jj * 64 + lane];
      float aj0 = __int_as_float(__builtin_amdgcn_readlane(__float_as_int(ca0), j));
      float cj0 = __int_as_float(__builtin_amdgcn_readlane(__float_as_int(cc0), j));
      float dj0 = __int_as_float(__builtin_amdgcn_readlane(__float_as_int(cd0), j));
      float aj1 = __int_as_float(__builtin_amdgcn_readlane(__float_as_int(ca1), j));
      float cj1 = __int_as_float(__builtin_amdgcn_readlane(__float_as_int(cc1), j));
      float dj1 = __int_as_float(__builtin_amdgcn_readlane(__float_as_int(cd1), j));
      bool own = (lane == j);
      ka0 = own ? ca0 : ka0; kc0 = own ? cc0 : kc0; kd0 = own ? cd0 : kd0;
      ka1 = own ? ca1 : ka1; kc1 = own ? cc1 : kc1; kd1 = own ? cd1 : kd1;
      pW0 = fmaf(wa, aj0, pW0); pW0 = fmaf(wc, cj0, pW0); pW0 = fmaf(wd, dj0, pW0);
      pM0 = fmaf(ma, aj0, pM0); pM0 = fmaf(mc, cj0, pM0); pM0 = fmaf(md, dj0, pM0);
      pB0 = fmaf(ba, aj0, pB0); pB0 = fmaf(bc, cj0, pB0); pB0 = fmaf(bd, dj0, pB0);
      pW1 = fmaf(wa, aj1, pW1); pW1 = fmaf(wc, cj1, pW1); pW1 = fmaf(wd, dj1, pW1);
      pM1 = fmaf(ma, aj1, pM1); pM1 = fmaf(mc, cj1, pM1); pM1 = fmaf(md, dj1, pM1);
      pB1 = fmaf(ba, aj1, pB1); pB1 = fmaf(bc, cj1, pB1); pB1 = fmaf(bd, dj1, pB1);
      ca0 = e2x - pW0; cc0 = pW0 - pM0; cd0 = e1x - pB0;
      ca1 = e2y - pW1; cc1 = pW1 - pM1; cd1 = e1y - pB1;
    }
  }
  acd[eoff + f0] = make_float4(ka0, kc0, kd0, 0.f);
  acd[eoff + f1] = make_float4(ka1, kc1, kd1, 0.f);
}

// ---------------------------------------------------------------------------
// K_infer (unchanged)
// ---------------------------------------------------------------------------
__global__ __launch_bounds__(1024) void k_infer(
    const float4* __restrict__ acd,
    const float* __restrict__ e1, const float* __restrict__ e2,
    const float* __restrict__ r1, const float* __restrict__ r2,
    const float* __restrict__ r3,
    const float* __restrict__ qe1, const float* __restrict__ qr1,
    const float* __restrict__ qr2, const float* __restrict__ qr3,
    const float* __restrict__ lng, const float* __restrict__ lnb,
    float* __restrict__ isum) {
  int b = blockIdx.x, tid = threadIdx.x;
  __shared__ float hista[64 * 65], histc[64 * 65], histd[64 * 65];
  __shared__ float vlds[9 * 64];
  __shared__ float ivec[64];
  __shared__ float u1s[64], u2s[64];
  __shared__ float dsc[64];

  {
    const float4* ab = acd + (long)b * 4096;
    for (int idx = tid; idx < 4096; idx += 1024) {
      float4 hv = ab[idx];
      int j = idx >> 6, f = idx & 63;
      hista[j * 65 + f] = hv.x;
      histc[j * 65 + f] = hv.y;
      histd[j * 65 + f] = hv.z;
    }
  }
  if (tid < 576) {
    int pk = tid >> 6, j = tid & 63;
    int p = pk / 3, k = pk % 3;
    const float* rv = ((k == 0) ? r1 : (k == 1) ? r2 : r3) + ((long)b * 64 + j) * 32;
    const float* q = ((p == 0) ? qr1 : (p == 1) ? qr2 : qr3) + b * 32;
    float acc = 0.f;
#pragma unroll
    for (int t = 0; t < 8; ++t) {
      float4 rv4 = *(const float4*)(rv + 4 * t);
      float4 q4 = *(const float4*)(q + 4 * t);
      acc = fmaf(rv4.x, q4.x, fmaf(rv4.y, q4.y,
            fmaf(rv4.z, q4.z, fmaf(rv4.w, q4.w, acc))));
    }
    vlds[pk * 64 + j] = acc;
  }
  if (tid < 64) ivec[tid] = qe1[b * 64 + tid];
  __syncthreads();

  int f = tid >> 4, jsl = tid & 15;
  int dotd = tid >> 3, dt = tid & 7;
  int which = dotd >> 6, dj = dotd & 63;
  const float* erow = (which ? e2 : e1) + ((long)b * 64 + dj) * 64 + dt * 8;
  float isacc = 0.f;
  for (int p = 0; p < 3; ++p) {
    {
      float acc = 0.f;
#pragma unroll
      for (int t = 0; t < 8; ++t)
        acc = fmaf(erow[t], ivec[dt * 8 + t], acc);
      acc += __shfl_xor(acc, 1, 64);
      acc += __shfl_xor(acc, 2, 64);
      acc += __shfl_xor(acc, 4, 64);
      if (dt == 0) { if (which) u2s[dj] = acc; else u1s[dj] = acc; }
    }
    __syncthreads();
    float part = 0.f;
#pragma unroll
    for (int i = 0; i < 4; ++i) {
      int j = jsl * 4 + i;
      float ca = u1s[j] * vlds[(p * 3 + 0) * 64 + j];
      float cc = u1s[j] * vlds[(p * 3 + 1) * 64 + j];
      float cd = u2s[j] * vlds[(p * 3 + 2) * 64 + j];
      part = fmaf(ca, hista[j * 65 + f],
             fmaf(cc, histc[j * 65 + f],
             fmaf(cd, histd[j * 65 + f], part)));
    }
    part += __shfl_xor(part, 1, 64);
    part += __shfl_xor(part, 2, 64);
    part += __shfl_xor(part, 4, 64);
    part += __shfl_xor(part, 8, 64);
    if (jsl == 0) dsc[f] = part;
    __syncthreads();
    if (tid < 64) {
      float v = dsc[tid];
      float mu = v;
#pragma unroll
      for (int mm = 1; mm <= 32; mm <<= 1) mu += __shfl_xor(mu, mm, 64);
      mu *= (1.f / 64.f);
      float d = v - mu;
      float vr = d * d;
#pragma unroll
      for (int mm = 1; mm <= 32; mm <<= 1) vr += __shfl_xor(vr, mm, 64);
      vr *= (1.f / 64.f);
      float iv = d * (1.f / sqrtf(vr + 1e-5f)) * lng[p * 64 + tid] + lnb[p * 64 + tid];
      ivec[tid] = iv;
      isacc += iv;
    }
    __syncthreads();
  }
  if (tid < 64) isum[b * 64 + tid] = isacc;
}

// ---------------------------------------------------------------------------
// K5: out[b,v] = sum_e isum[b,e] * Z[e,v]   (unchanged)
// ---------------------------------------------------------------------------
__global__ __launch_bounds__(256) void k_final(
    const float* __restrict__ isum, const float* __restrict__ Zm,
    float* __restrict__ out) {
  __shared__ float isT[64 * 68];
  int tid = threadIdx.x;
  for (int i = tid; i < 4096; i += 256) {
    int bb = i >> 6, e = i & 63;
    isT[e * 68 + bb] = isum[i];
  }
  __syncthreads();
  int tr = tid >> 4, tc = tid & 15;
  int v0 = blockIdx.x * 64 + tc * 4;
  float acc[4][4] = {};
#pragma unroll 2
  for (int e = 0; e < 64; ++e) {
    float4 a4 = *(const float4*)&isT[e * 68 + 4 * tr];
    float4 z4 = *(const float4*)(Zm + (long)e * V_ + v0);
    float as[4] = {a4.x, a4.y, a4.z, a4.w};
    float zs[4] = {z4.x, z4.y, z4.z, z4.w};
#pragma unroll
    for (int i = 0; i < 4; ++i)
#pragma unroll
      for (int j = 0; j < 4; ++j) acc[i][j] = fmaf(as[i], zs[j], acc[i][j]);
  }
#pragma unroll
  for (int i = 0; i < 4; ++i) {
    float4 o4 = make_float4(acc[i][0], acc[i][1], acc[i][2], acc[i][3]);
    *(float4*)(out + (long)(4 * tr + i) * V_ + v0) = o4;
  }
}

// ---------------------------------------------------------------------------
extern "C" void kernel_launch(void* const* d_in, const int* in_sizes, int n_in,
                              void* d_out, int out_size, void* d_ws, size_t ws_size,
                              hipStream_t stream) {
  const int* story = (const int*)d_in[0];
  const int* query = (const int*)d_in[1];
  const float* we = (const float*)d_in[2];
  const float* pe = (const float*)d_in[3];
  const float* ueW1 = (const float*)d_in[4];
  const float* ueb1 = (const float*)d_in[5];
  const float* ueW2 = (const float*)d_in[6];
  const float* ueb2 = (const float*)d_in[7];
  const float* urW1 = (const float*)d_in[8];
  const float* urb1 = (const float*)d_in[9];
  const float* urW2 = (const float*)d_in[10];
  const float* urb2 = (const float*)d_in[11];
  const float* ieW1 = (const float*)d_in[12];
  const float* ieb1 = (const float*)d_in[13];
  const float* ieW2 = (const float*)d_in[14];
  const float* ieb2 = (const float*)d_in[15];
  const float* irW1 = (const float*)d_in[16];
  const float* irb1 = (const float*)d_in[17];
  const float* irW2 = (const float*)d_in[18];
  const float* irb2 = (const float*)d_in[19];
  const float* lng = (const float*)d_in[20];
  const float* lnb = (const float*)d_in[21];
  const float* Zm = (const float*)d_in[22];

  float* ws = (float*)d_ws;
  float* X = ws;                        // 4160*128 = 532480
  float* e1 = X + 532480;               // 4160*64  = 266240
  float* e2 = e1 + 266240;              // 266240
  float* r1 = e2 + 266240;              // 4160*32  = 133120
  float* r2 = r1 + 133120;              // 133120
  float* r3 = r2 + 133120;              // 133120
  float* isum = r3 + 133120;            // 4096
  float* Wt = isum + 4096;              // 9*64*4096 = 2359296
  float4* acd = (float4*)(Wt + 2359296);  // 64*64*64 float4 = 4 MB
  float* qe1 = e1 + 4096 * 64;
  float* qr1 = r1 + 4096 * 32;
  float* qr2 = r2 + 4096 * 32;
  float* qr3 = r3 + 4096 * 32;
  float* outF = (float*)d_out;

  k_embed<<<4160, 128, 0, stream>>>(story, query, we, pe, X);
  k_mlp<<<520 * 5, 64, 0, stream>>>(X, ueW1, ueb1, ueW2, ueb2,
                                    urW1, urb1, urW2, urb2,
                                    ieW1, ieb1, ieW2, ieb2,
                                    irW1, irb1, irW2, irb2,
                                    e1, e2, r1, r2, r3);
  k_gram<<<64 * 9, 256, 0, stream>>>(e1, e2, r1, r2, r3, Wt);
  k_scan<<<512, 256, 0, stream>>>(e1, e2, Wt, acd);
  k_infer<<<B_, 1024, 0, stream>>>(acd, e1, e2, r1, r2, r3, qe1, qr1, qr2, qr3,
                                   lng, lnb, isum);
  k_final<<<V_ / 64, 256, 0, stream>>>(isum, Zm, outF);
}

// Round 3
// 223.295 us; speedup vs baseline: 1.1437x; 1.1437x over previous
//
#include <hip/hip_runtime.h>
#include <math.h>

// Problem constants
#define B_   64
#define S_   64
#define W_   12
#define V_   32000
#define SYM_ 128
#define HID_ 256
#define E_   64
#define R_   32

// wave-local LDS fence: all prior DS ops complete, compiler may not reorder
#define WAVE_FENCE() asm volatile("s_waitcnt lgkmcnt(0)" ::: "memory")

__device__ __forceinline__ float fast_tanh(float x) {
  // tanh(x) = 1 - 2/(e^{2x}+1); v_exp + v_rcp, ~1e-7 abs error, saturates correctly
  float e = __expf(2.0f * x);
  return 1.0f - 2.0f * __builtin_amdgcn_rcpf(e + 1.0f);
}

// ---------------------------------------------------------------------------
// K1: embedding sums for story (rows 0..4095) and query (rows 4096..4159)
// ---------------------------------------------------------------------------
__global__ __launch_bounds__(128) void k_embed(
    const int* __restrict__ story, const int* __restrict__ query,
    const float* __restrict__ we, const float* __restrict__ pe,
    float* __restrict__ X) {
  int row = blockIdx.x;
  int e = threadIdx.x;
  const int* idx = (row < 4096) ? story + row * W_ : query + (row - 4096) * W_;
  float acc = 0.f;
#pragma unroll
  for (int w = 0; w < W_; ++w)
    acc = fmaf(we[(long)idx[w] * SYM_ + e], pe[w * SYM_ + e], acc);
  X[row * SYM_ + e] = acc;
}

// ---------------------------------------------------------------------------
// K2 v10: barrier-free MLP, row-half split to halve LDS bytes returned.
// Block = 128 thr (2 waves), 16-row tile, 1 head; grid 1300 (5.1 blk/CU).
// Wave = 8 rows, wave-private LDS (XT 8x132 overlaid by HT 8x260). Lane
// row-half lh=l>>5: L1 lane covers 4 rows x 8 cols -> X b128 reads per kg
// 8->4 (each instr serves both halves' rows); L2-E lane covers 4 rows x
// 2 cols -> H reads per c4 8->4. LDS pipe cost is per-KB-returned, so
// halving instr count at same fma halves the binding resource. Stride 132
// for XT so the two halves' broadcast addresses hit different banks.
// ---------------------------------------------------------------------------
__global__ __launch_bounds__(128) void k_mlp(
    const float* __restrict__ X,
    const float* __restrict__ ueW1, const float* __restrict__ ueb1,
    const float* __restrict__ ueW2, const float* __restrict__ ueb2,
    const float* __restrict__ urW1, const float* __restrict__ urb1,
    const float* __restrict__ urW2, const float* __restrict__ urb2,
    const float* __restrict__ ieW1, const float* __restrict__ ieb1,
    const float* __restrict__ ieW2, const float* __restrict__ ieb2,
    const float* __restrict__ irW1, const float* __restrict__ irb1,
    const float* __restrict__ irW2, const float* __restrict__ irb2,
    float* __restrict__ oE0, float* __restrict__ oE1,
    float* __restrict__ oR0, float* __restrict__ oR1, float* __restrict__ oR2) {
  // 2 waves x 2080 floats. Per wave: XT [8][132]=1056 overlaid by HT [8][260]=2080.
  __shared__ float SM[2 * 2080];

  int h = blockIdx.x % 5;
  int tile = blockIdx.x / 5;
  int rowbase = tile * 16;
  bool isQ = (rowbase >= 4096);
  bool isE = (h < 2);
  const float* W1 = isE ? (isQ ? ieW1 : ueW1) + h * (SYM_ * HID_)
                        : (isQ ? irW1 : urW1) + (h - 2) * (SYM_ * HID_);
  const float* b1 = isE ? (isQ ? ieb1 : ueb1) + h * HID_
                        : (isQ ? irb1 : urb1) + (h - 2) * HID_;
  const float* W2 = isE ? (isQ ? ieW2 : ueW2) + h * (HID_ * E_)
                        : (isQ ? irW2 : urW2) + (h - 2) * (HID_ * R_);
  const float* b2 = isE ? (isQ ? ieb2 : ueb2) + h * E_
                        : (isQ ? irb2 : urb2) + (h - 2) * R_;
  float* out = (h == 0) ? oE0 : (h == 1) ? oE1 : (h == 2) ? oR0 : (h == 3) ? oR1 : oR2;

  int tid = threadIdx.x;
  int wv = tid >> 6;     // wave 0..1: rows 8wv..8wv+7
  int l = tid & 63;      // lane
  int lh = l >> 5;       // row-half: rows 4lh..4lh+3 within the wave's 8
  int ll = l & 31;
  float* WS = SM + wv * 2080;  // wave-private region

  // stage this wave's 8 rows of X, layout [row][k] stride 132 (bank-stagger)
#pragma unroll
  for (int c = 0; c < 4; ++c) {
    int i = l + 64 * c;               // 0..255
    int row = i >> 5, k4 = (i & 31) * 4;
    *(float4*)&WS[row * 132 + k4] =
        *(const float4*)(X + (long)(rowbase + 8 * wv + row) * SYM_ + k4);
  }
  WAVE_FENCE();  // cross-lane RAW within the wave

  // layer 1: lane computes rows 4lh..4lh+3, cols 8ll..8ll+7
  float a[4][8];
#pragma unroll
  for (int i = 0; i < 4; ++i)
#pragma unroll
    for (int q = 0; q < 8; ++q) a[i][q] = 0.f;

  const float* W1p = W1 + 8 * ll;
#pragma unroll 2
  for (int kg = 0; kg < 32; ++kg) {
    float4 wlo[4], whi[4];
#pragma unroll
    for (int j = 0; j < 4; ++j) {
      wlo[j] = *(const float4*)(W1p + (long)(4 * kg + j) * HID_);
      whi[j] = *(const float4*)(W1p + (long)(4 * kg + j) * HID_ + 4);
    }
    float4 xr[4];
#pragma unroll
    for (int i = 0; i < 4; ++i)
      xr[i] = *(const float4*)&WS[(4 * lh + i) * 132 + 4 * kg];  // 2-addr broadcast
#pragma unroll
    for (int i = 0; i < 4; ++i) {
      float xj[4] = {xr[i].x, xr[i].y, xr[i].z, xr[i].w};
#pragma unroll
      for (int j = 0; j < 4; ++j) {
        a[i][0] = fmaf(xj[j], wlo[j].x, a[i][0]);
        a[i][1] = fmaf(xj[j], wlo[j].y, a[i][1]);
        a[i][2] = fmaf(xj[j], wlo[j].z, a[i][2]);
        a[i][3] = fmaf(xj[j], wlo[j].w, a[i][3]);
        a[i][4] = fmaf(xj[j], whi[j].x, a[i][4]);
        a[i][5] = fmaf(xj[j], whi[j].y, a[i][5]);
        a[i][6] = fmaf(xj[j], whi[j].z, a[i][6]);
        a[i][7] = fmaf(xj[j], whi[j].w, a[i][7]);
      }
    }
  }

  // bias + tanh -> HT[row][c], stride 260; lane writes its 4 rows x 8 cols
  {
    float4 b1lo = *(const float4*)(b1 + 8 * ll);
    float4 b1hi = *(const float4*)(b1 + 8 * ll + 4);
#pragma unroll
    for (int i = 0; i < 4; ++i) {
      float4 lo = make_float4(fast_tanh(a[i][0] + b1lo.x), fast_tanh(a[i][1] + b1lo.y),
                              fast_tanh(a[i][2] + b1lo.z), fast_tanh(a[i][3] + b1lo.w));
      float4 hi = make_float4(fast_tanh(a[i][4] + b1hi.x), fast_tanh(a[i][5] + b1hi.y),
                              fast_tanh(a[i][6] + b1hi.z), fast_tanh(a[i][7] + b1hi.w));
      *(float4*)&WS[(4 * lh + i) * 260 + 8 * ll] = lo;
      *(float4*)&WS[(4 * lh + i) * 260 + 8 * ll + 4] = hi;
    }
  }
  WAVE_FENCE();  // cross-lane RAW before layer-2 reads

  if (isE) {
    // layer 2 E: lane = rows 4lh..4lh+3, cols {2ll, 2ll+1}
    float2 acc[4];
#pragma unroll
    for (int i = 0; i < 4; ++i) acc[i] = make_float2(0.f, 0.f);
#pragma unroll 2
    for (int c4 = 0; c4 < 64; ++c4) {
      float2 w0 = *(const float2*)(W2 + (long)(4 * c4 + 0) * E_ + 2 * ll);
      float2 w1 = *(const float2*)(W2 + (long)(4 * c4 + 1) * E_ + 2 * ll);
      float2 w2 = *(const float2*)(W2 + (long)(4 * c4 + 2) * E_ + 2 * ll);
      float2 w3 = *(const float2*)(W2 + (long)(4 * c4 + 3) * E_ + 2 * ll);
#pragma unroll
      for (int i = 0; i < 4; ++i) {
        float4 hh = *(const float4*)&WS[(4 * lh + i) * 260 + 4 * c4];  // 2-addr bcast
        acc[i].x = fmaf(hh.x, w0.x, fmaf(hh.y, w1.x, fmaf(hh.z, w2.x, fmaf(hh.w, w3.x, acc[i].x))));
        acc[i].y = fmaf(hh.x, w0.y, fmaf(hh.y, w1.y, fmaf(hh.z, w2.y, fmaf(hh.w, w3.y, acc[i].y))));
      }
    }
    float2 bb = *(const float2*)(b2 + 2 * ll);
#pragma unroll
    for (int i = 0; i < 4; ++i) {
      float2 o = make_float2(acc[i].x + bb.x, acc[i].y + bb.y);
      *(float2*)&out[(long)(rowbase + 8 * wv + 4 * lh + i) * E_ + 2 * ll] = o;
    }
  } else {
    // layer 2 R: lane = col ll for all 8 rows, c4-range split by half + reduce
    float acc[8];
#pragma unroll
    for (int i = 0; i < 8; ++i) acc[i] = 0.f;
    int c4base = lh * 32;
#pragma unroll 2
    for (int c4o = 0; c4o < 32; ++c4o) {
      int c4 = c4base + c4o;
      float w0 = W2[(long)(4 * c4 + 0) * R_ + ll];
      float w1 = W2[(long)(4 * c4 + 1) * R_ + ll];
      float w2 = W2[(long)(4 * c4 + 2) * R_ + ll];
      float w3 = W2[(long)(4 * c4 + 3) * R_ + ll];
#pragma unroll
      for (int i = 0; i < 8; ++i) {
        float4 hh = *(const float4*)&WS[i * 260 + 4 * c4];
        acc[i] = fmaf(hh.x, w0, fmaf(hh.y, w1, fmaf(hh.z, w2, fmaf(hh.w, w3, acc[i]))));
      }
    }
#pragma unroll
    for (int i = 0; i < 8; ++i) acc[i] += __shfl_xor(acc[i], 32, 64);
    if (l < 32) {
      float bb = b2[ll];
#pragma unroll
      for (int i = 0; i < 8; ++i)
        out[(long)(rowbase + 8 * wv + i) * R_ + ll] = acc[i] + bb;
    }
  }
}

// ---------------------------------------------------------------------------
// K_gram v2: writes TRANSPOSED Wt[b][m][j][s]  (unchanged)
// ---------------------------------------------------------------------------
__global__ __launch_bounds__(256) void k_gram(
    const float* __restrict__ e1, const float* __restrict__ e2,
    const float* __restrict__ r1, const float* __restrict__ r2,
    const float* __restrict__ r3, float* __restrict__ Wt) {
  int b = blockIdx.x / 9, m = blockIdx.x % 9;
  const float* sE = ((m < 6) ? e1 : e2) + (long)b * S_ * E_;
  const float* jE = ((m == 2 || m == 5 || m == 8) ? e2 : e1) + (long)b * S_ * E_;
  int sk = m / 3, jk = m % 3;
  const float* sR = ((sk == 0) ? r1 : (sk == 1) ? r2 : r3) + (long)b * S_ * R_;
  const float* jR = ((jk == 0) ? r1 : (jk == 1) ? r2 : r3) + (long)b * S_ * R_;

  __shared__ float Es[64][68], Ej[64][68], Rs[64][36], Rj[64][36];
  int tid = threadIdx.x;
  for (int i = tid; i < 1024; i += 256) {
    int row = i >> 4, c = i & 15;
    *(float4*)&Es[row][4 * c] = *(const float4*)(sE + row * 64 + 4 * c);
    *(float4*)&Ej[row][4 * c] = *(const float4*)(jE + row * 64 + 4 * c);
  }
  for (int i = tid; i < 512; i += 256) {
    int row = i >> 3, c = i & 7;
    *(float4*)&Rs[row][4 * c] = *(const float4*)(sR + row * 32 + 4 * c);
    *(float4*)&Rj[row][4 * c] = *(const float4*)(jR + row * 32 + 4 * c);
  }
  __syncthreads();

  int s0 = (tid & 15) * 4, j0 = (tid >> 4) * 4;
  float ed[4][4] = {}, rd[4][4] = {};  // [s][j]
#pragma unroll 4
  for (int k = 0; k < 16; ++k) {
    float4 es[4], ej[4];
#pragma unroll
    for (int i = 0; i < 4; ++i) {
      es[i] = *(const float4*)&Es[s0 + i][4 * k];
      ej[i] = *(const float4*)&Ej[j0 + i][4 * k];
    }
#pragma unroll
    for (int i = 0; i < 4; ++i)
#pragma unroll
      for (int j = 0; j < 4; ++j)
        ed[i][j] = fmaf(es[i].x, ej[j].x, fmaf(es[i].y, ej[j].y,
                   fmaf(es[i].z, ej[j].z, fmaf(es[i].w, ej[j].w, ed[i][j]))));
  }
#pragma unroll 4
  for (int k = 0; k < 8; ++k) {
    float4 rs[4], rj[4];
#pragma unroll
    for (int i = 0; i < 4; ++i) {
      rs[i] = *(const float4*)&Rs[s0 + i][4 * k];
      rj[i] = *(const float4*)&Rj[j0 + i][4 * k];
    }
#pragma unroll
    for (int i = 0; i < 4; ++i)
#pragma unroll
      for (int j = 0; j < 4; ++j)
        rd[i][j] = fmaf(rs[i].x, rj[j].x, fmaf(rs[i].y, rj[j].y,
                   fmaf(rs[i].z, rj[j].z, fmaf(rs[i].w, rj[j].w, rd[i][j]))));
  }
  float* wout = Wt + (long)(b * 9 + m) * 4096;
#pragma unroll
  for (int jj = 0; jj < 4; ++jj) {
    float4 o4 = make_float4(ed[0][jj] * rd[0][jj], ed[1][jj] * rd[1][jj],
                            ed[2][jj] * rd[2][jj], ed[3][jj] * rd[3][jj]);
    *(float4*)(wout + (j0 + jj) * 64 + s0) = o4;  // [j][s]
  }
}

// ---------------------------------------------------------------------------
// K_scan v6 (unchanged): outer-product recurrence, LDS-staged Wt.
// ---------------------------------------------------------------------------
__global__ __launch_bounds__(256) void k_scan(
    const float* __restrict__ e1g, const float* __restrict__ e2g,
    const float* __restrict__ Wt, float4* __restrict__ acd) {
  __shared__ float WtL[9 * 512];
  int b = blockIdx.x & 63;
  int g = blockIdx.x >> 6;
  int tid = threadIdx.x;
  int wv = tid >> 6;
  int lane = tid & 63;             // = s
  int f0 = g * 8 + wv * 2;
  int f1 = f0 + 1;
  const float* Wb = Wt + (long)b * 9 * 4096;
  long eoff = ((long)b * 64 + lane) * 64;
  float e1x = e1g[eoff + f0], e1y = e1g[eoff + f1];
  float e2x = e2g[eoff + f0], e2y = e2g[eoff + f1];

  float pW0 = 0.f, pM0 = 0.f, pB0 = 0.f;
  float pW1 = 0.f, pM1 = 0.f, pB1 = 0.f;
  float ca0 = e2x, cc0 = 0.f, cd0 = e1x;
  float ca1 = e2y, cc1 = 0.f, cd1 = e1y;
  float ka0 = 0.f, kc0 = 0.f, kd0 = 0.f;
  float ka1 = 0.f, kc1 = 0.f, kd1 = 0.f;

  for (int jc = 0; jc < 8; ++jc) {
    __syncthreads();
    for (int i = tid; i < 1152; i += 256) {
      int m = i >> 7;
      int off = (i & 127) * 4;
      *(float4*)&WtL[m * 512 + off] = *(const float4*)(Wb + m * 4096 + jc * 512 + off);
    }
    __syncthreads();
#pragma unroll
    for (int jj = 0; jj < 8; ++jj) {
      int j = jc * 8 + jj;
      float wa = WtL[0 * 512 + jj * 64 + lane];
      float wc = WtL[1 * 512 + jj * 64 + lane];
      float wd = WtL[2 * 512 + jj * 64 + lane];
      float ma = WtL[3 * 512 + jj * 64 + lane];
      float mc = WtL[4 * 512 + jj * 64 + lane];
      float md = WtL[5 * 512 + jj * 64 + lane];
      float ba = WtL[6 * 512 + jj * 64 + lane];
      float bc = WtL[7 * 512 + jj * 64 + lane];
      float bd = WtL[8 * 512 + jj * 64 + lane];
      float aj0 = __int_as_float(__builtin_amdgcn_readlane(__float_as_int(ca0), j));
      float cj0 = __int_as_float(__builtin_amdgcn_readlane(__float_as_int(cc0), j));
      float dj0 = __int_as_float(__builtin_amdgcn_readlane(__float_as_int(cd0), j));
      float aj1 = __int_as_float(__builtin_amdgcn_readlane(__float_as_int(ca1), j));
      float cj1 = __int_as_float(__builtin_amdgcn_readlane(__float_as_int(cc1), j));
      float dj1 = __int_as_float(__builtin_amdgcn_readlane(__float_as_int(cd1), j));
      bool own = (lane == j);
      ka0 = own ? ca0 : ka0; kc0 = own ? cc0 : kc0; kd0 = own ? cd0 : kd0;
      ka1 = own ? ca1 : ka1; kc1 = own ? cc1 : kc1; kd1 = own ? cd1 : kd1;
      pW0 = fmaf(wa, aj0, pW0); pW0 = fmaf(wc, cj0, pW0); pW0 = fmaf(wd, dj0, pW0);
      pM0 = fmaf(ma, aj0, pM0); pM0 = fmaf(mc, cj0, pM0); pM0 = fmaf(md, dj0, pM0);
      pB0 = fmaf(ba, aj0, pB0); pB0 = fmaf(bc, cj0, pB0); pB0 = fmaf(bd, dj0, pB0);
      pW1 = fmaf(wa, aj1, pW1); pW1 = fmaf(wc, cj1, pW1); pW1 = fmaf(wd, dj1, pW1);
      pM1 = fmaf(ma, aj1, pM1); pM1 = fmaf(mc, cj1, pM1); pM1 = fmaf(md, dj1, pM1);
      pB1 = fmaf(ba, aj1, pB1); pB1 = fmaf(bc, cj1, pB1); pB1 = fmaf(bd, dj1, pB1);
      ca0 = e2x - pW0; cc0 = pW0 - pM0; cd0 = e1x - pB0;
      ca1 = e2y - pW1; cc1 = pW1 - pM1; cd1 = e1y - pB1;
    }
  }
  acd[eoff + f0] = make_float4(ka0, kc0, kd0, 0.f);
  acd[eoff + f1] = make_float4(ka1, kc1, kd1, 0.f);
}

// ---------------------------------------------------------------------------
// K_infer (unchanged)
// ---------------------------------------------------------------------------
__global__ __launch_bounds__(1024) void k_infer(
    const float4* __restrict__ acd,
    const float* __restrict__ e1, const float* __restrict__ e2,
    const float* __restrict__ r1, const float* __restrict__ r2,
    const float* __restrict__ r3,
    const float* __restrict__ qe1, const float* __restrict__ qr1,
    const float* __restrict__ qr2, const float* __restrict__ qr3,
    const float* __restrict__ lng, const float* __restrict__ lnb,
    float* __restrict__ isum) {
  int b = blockIdx.x, tid = threadIdx.x;
  __shared__ float hista[64 * 65], histc[64 * 65], histd[64 * 65];
  __shared__ float vlds[9 * 64];
  __shared__ float ivec[64];
  __shared__ float u1s[64], u2s[64];
  __shared__ float dsc[64];

  {
    const float4* ab = acd + (long)b * 4096;
    for (int idx = tid; idx < 4096; idx += 1024) {
      float4 hv = ab[idx];
      int j = idx >> 6, f = idx & 63;
      hista[j * 65 + f] = hv.x;
      histc[j * 65 + f] = hv.y;
      histd[j * 65 + f] = hv.z;
    }
  }
  if (tid < 576) {
    int pk = tid >> 6, j = tid & 63;
    int p = pk / 3, k = pk % 3;
    const float* rv = ((k == 0) ? r1 : (k == 1) ? r2 : r3) + ((long)b * 64 + j) * 32;
    const float* q = ((p == 0) ? qr1 : (p == 1) ? qr2 : qr3) + b * 32;
    float acc = 0.f;
#pragma unroll
    for (int t = 0; t < 8; ++t) {
      float4 rv4 = *(const float4*)(rv + 4 * t);
      float4 q4 = *(const float4*)(q + 4 * t);
      acc = fmaf(rv4.x, q4.x, fmaf(rv4.y, q4.y,
            fmaf(rv4.z, q4.z, fmaf(rv4.w, q4.w, acc))));
    }
    vlds[pk * 64 + j] = acc;
  }
  if (tid < 64) ivec[tid] = qe1[b * 64 + tid];
  __syncthreads();

  int f = tid >> 4, jsl = tid & 15;
  int dotd = tid >> 3, dt = tid & 7;
  int which = dotd >> 6, dj = dotd & 63;
  const float* erow = (which ? e2 : e1) + ((long)b * 64 + dj) * 64 + dt * 8;
  float isacc = 0.f;
  for (int p = 0; p < 3; ++p) {
    {
      float acc = 0.f;
#pragma unroll
      for (int t = 0; t < 8; ++t)
        acc = fmaf(erow[t], ivec[dt * 8 + t], acc);
      acc += __shfl_xor(acc, 1, 64);
      acc += __shfl_xor(acc, 2, 64);
      acc += __shfl_xor(acc, 4, 64);
      if (dt == 0) { if (which) u2s[dj] = acc; else u1s[dj] = acc; }
    }
    __syncthreads();
    float part = 0.f;
#pragma unroll
    for (int i = 0; i < 4; ++i) {
      int j = jsl * 4 + i;
      float ca = u1s[j] * vlds[(p * 3 + 0) * 64 + j];
      float cc = u1s[j] * vlds[(p * 3 + 1) * 64 + j];
      float cd = u2s[j] * vlds[(p * 3 + 2) * 64 + j];
      part = fmaf(ca, hista[j * 65 + f],
             fmaf(cc, histc[j * 65 + f],
             fmaf(cd, histd[j * 65 + f], part)));
    }
    part += __shfl_xor(part, 1, 64);
    part += __shfl_xor(part, 2, 64);
    part += __shfl_xor(part, 4, 64);
    part += __shfl_xor(part, 8, 64);
    if (jsl == 0) dsc[f] = part;
    __syncthreads();
    if (tid < 64) {
      float v = dsc[tid];
      float mu = v;
#pragma unroll
      for (int mm = 1; mm <= 32; mm <<= 1) mu += __shfl_xor(mu, mm, 64);
      mu *= (1.f / 64.f);
      float d = v - mu;
      float vr = d * d;
#pragma unroll
      for (int mm = 1; mm <= 32; mm <<= 1) vr += __shfl_xor(vr, mm, 64);
      vr *= (1.f / 64.f);
      float iv = d * (1.f / sqrtf(vr + 1e-5f)) * lng[p * 64 + tid] + lnb[p * 64 + tid];
      ivec[tid] = iv;
      isacc += iv;
    }
    __syncthreads();
  }
  if (tid < 64) isum[b * 64 + tid] = isacc;
}

// ---------------------------------------------------------------------------
// K5: out[b,v] = sum_e isum[b,e] * Z[e,v]   (unchanged)
// ---------------------------------------------------------------------------
__global__ __launch_bounds__(256) void k_final(
    const float* __restrict__ isum, const float* __restrict__ Zm,
    float* __restrict__ out) {
  __shared__ float isT[64 * 68];
  int tid = threadIdx.x;
  for (int i = tid; i < 4096; i += 256) {
    int bb = i >> 6, e = i & 63;
    isT[e * 68 + bb] = isum[i];
  }
  __syncthreads();
  int tr = tid >> 4, tc = tid & 15;
  int v0 = blockIdx.x * 64 + tc * 4;
  float acc[4][4] = {};
#pragma unroll 2
  for (int e = 0; e < 64; ++e) {
    float4 a4 = *(const float4*)&isT[e * 68 + 4 * tr];
    float4 z4 = *(const float4*)(Zm + (long)e * V_ + v0);
    float as[4] = {a4.x, a4.y, a4.z, a4.w};
    float zs[4] = {z4.x, z4.y, z4.z, z4.w};
#pragma unroll
    for (int i = 0; i < 4; ++i)
#pragma unroll
      for (int j = 0; j < 4; ++j) acc[i][j] = fmaf(as[i], zs[j], acc[i][j]);
  }
#pragma unroll
  for (int i = 0; i < 4; ++i) {
    float4 o4 = make_float4(acc[i][0], acc[i][1], acc[i][2], acc[i][3]);
    *(float4*)(out + (long)(4 * tr + i) * V_ + v0) = o4;
  }
}

// ---------------------------------------------------------------------------
extern "C" void kernel_launch(void* const* d_in, const int* in_sizes, int n_in,
                              void* d_out, int out_size, void* d_ws, size_t ws_size,
                              hipStream_t stream) {
  const int* story = (const int*)d_in[0];
  const int* query = (const int*)d_in[1];
  const float* we = (const float*)d_in[2];
  const float* pe = (const float*)d_in[3];
  const float* ueW1 = (const float*)d_in[4];
  const float* ueb1 = (const float*)d_in[5];
  const float* ueW2 = (const float*)d_in[6];
  const float* ueb2 = (const float*)d_in[7];
  const float* urW1 = (const float*)d_in[8];
  const float* urb1 = (const float*)d_in[9];
  const float* urW2 = (const float*)d_in[10];
  const float* urb2 = (const float*)d_in[11];
  const float* ieW1 = (const float*)d_in[12];
  const float* ieb1 = (const float*)d_in[13];
  const float* ieW2 = (const float*)d_in[14];
  const float* ieb2 = (const float*)d_in[15];
  const float* irW1 = (const float*)d_in[16];
  const float* irb1 = (const float*)d_in[17];
  const float* irW2 = (const float*)d_in[18];
  const float* irb2 = (const float*)d_in[19];
  const float* lng = (const float*)d_in[20];
  const float* lnb = (const float*)d_in[21];
  const float* Zm = (const float*)d_in[22];

  float* ws = (float*)d_ws;
  float* X = ws;                        // 4160*128 = 532480
  float* e1 = X + 532480;               // 4160*64  = 266240
  float* e2 = e1 + 266240;              // 266240
  float* r1 = e2 + 266240;              // 4160*32  = 133120
  float* r2 = r1 + 133120;              // 133120
  float* r3 = r2 + 133120;              // 133120
  float* isum = r3 + 133120;            // 4096
  float* Wt = isum + 4096;              // 9*64*4096 = 2359296
  float4* acd = (float4*)(Wt + 2359296);  // 64*64*64 float4 = 4 MB
  float* qe1 = e1 + 4096 * 64;
  float* qr1 = r1 + 4096 * 32;
  float* qr2 = r2 + 4096 * 32;
  float* qr3 = r3 + 4096 * 32;
  float* outF = (float*)d_out;

  k_embed<<<4160, 128, 0, stream>>>(story, query, we, pe, X);
  k_mlp<<<260 * 5, 128, 0, stream>>>(X, ueW1, ueb1, ueW2, ueb2,
                                     urW1, urb1, urW2, urb2,
                                     ieW1, ieb1, ieW2, ieb2,
                                     irW1, irb1, irW2, irb2,
                                     e1, e2, r1, r2, r3);
  k_gram<<<64 * 9, 256, 0, stream>>>(e1, e2, r1, r2, r3, Wt);
  k_scan<<<512, 256, 0, stream>>>(e1, e2, Wt, acd);
  k_infer<<<B_, 1024, 0, stream>>>(acd, e1, e2, r1, r2, r3, qe1, qr1, qr2, qr3,
                                   lng, lnb, isum);
  k_final<<<V_ / 64, 256, 0, stream>>>(isum, Zm, outF);
}

// Round 4
// 197.864 us; speedup vs baseline: 1.2907x; 1.1285x over previous
//
#include <hip/hip_runtime.h>
#include <math.h>

// Problem constants
#define B_   64
#define S_   64
#define W_   12
#define V_   32000
#define SYM_ 128
#define HID_ 256
#define E_   64
#define R_   32

typedef short bf16x8 __attribute__((ext_vector_type(8)));
typedef float f32x4 __attribute__((ext_vector_type(4)));
#define MFMA16 __builtin_amdgcn_mfma_f32_16x16x32_bf16

__device__ __forceinline__ float fast_tanh(float x) {
  float e = __expf(2.0f * x);
  return 1.0f - 2.0f * __builtin_amdgcn_rcpf(e + 1.0f);
}

// fp32 -> bf16 hi (truncate) + bf16 lo (RNE of exact residual).
// hi trunc err <= 2^-8 |x|, residual exact (Sterbenz), lo RNE err 2^-9 of that
// -> combined representation error ~2^-17 |x|.
__device__ __forceinline__ void split1(float x, unsigned short& h, unsigned short& l) {
  unsigned u = __float_as_uint(x);
  h = (unsigned short)(u >> 16);
  float r = x - __uint_as_float(u & 0xFFFF0000u);
  unsigned v = __float_as_uint(r);
  l = (unsigned short)((v + 0x7FFFu + ((v >> 16) & 1u)) >> 16);
}

__device__ __forceinline__ void split8(const float4& a, const float4& b,
                                       bf16x8& h8, bf16x8& l8) {
  float xs[8] = {a.x, a.y, a.z, a.w, b.x, b.y, b.z, b.w};
#pragma unroll
  for (int j = 0; j < 8; ++j) {
    unsigned short hh, ll;
    split1(xs[j], hh, ll);
    h8[j] = (short)hh;
    l8[j] = (short)ll;
  }
}

// ---------------------------------------------------------------------------
// K1: embedding sums (unchanged)
// ---------------------------------------------------------------------------
__global__ __launch_bounds__(128) void k_embed(
    const int* __restrict__ story, const int* __restrict__ query,
    const float* __restrict__ we, const float* __restrict__ pe,
    float* __restrict__ X) {
  int row = blockIdx.x;
  int e = threadIdx.x;
  const int* idx = (row < 4096) ? story + row * W_ : query + (row - 4096) * W_;
  float acc = 0.f;
#pragma unroll
  for (int w = 0; w < W_; ++w)
    acc = fmaf(we[(long)idx[w] * SYM_ + e], pe[w * SYM_ + e], acc);
  X[row * SYM_ + e] = acc;
}

// ---------------------------------------------------------------------------
// K_wprep: split all 10 weight sets (ue/ur + ie/ir) into bf16 hi/lo and lay
// them out in per-lane MFMA B-fragment order so k_mlp loads frags with one
// coalesced b128 per lane.  k-convention: k = ks*32 + (lane>>4)*8 + j  (must
// match A-frag packing in k_mlp; any common k-permutation cancels in MFMA).
// W1p frag addr: ((slot*16+nt)*4+ks)*512 + lane*8   (slot = grp*5+h)
// W2p frag addr: ((slot*4 +nt)*8+ks)*512 + lane*8
// ---------------------------------------------------------------------------
__global__ __launch_bounds__(64) void k_wprep(
    const float* __restrict__ ueW1, const float* __restrict__ urW1,
    const float* __restrict__ ieW1, const float* __restrict__ irW1,
    const float* __restrict__ ueW2, const float* __restrict__ urW2,
    const float* __restrict__ ieW2, const float* __restrict__ irW2,
    unsigned short* __restrict__ w1ph, unsigned short* __restrict__ w1pl,
    unsigned short* __restrict__ w2ph, unsigned short* __restrict__ w2pl) {
  int l = threadIdx.x;
  int bid = blockIdx.x;
  bf16x8 h8, l8;
  if (bid < 640) {                      // W1 frags: 10 slots x 16 nt x 4 ks
    int slot = bid >> 6, rem = bid & 63;
    int nt = rem >> 2, ks = rem & 3;
    int grp = slot / 5, h = slot % 5;
    const float* src = (h < 2) ? ((grp ? ieW1 : ueW1) + h * (SYM_ * HID_))
                               : ((grp ? irW1 : urW1) + (h - 2) * (SYM_ * HID_));
    int kk = ks * 32 + (l >> 4) * 8;
    int n = nt * 16 + (l & 15);
#pragma unroll
    for (int j = 0; j < 8; ++j) {
      unsigned short hh, ll;
      split1(src[(long)(kk + j) * HID_ + n], hh, ll);
      h8[j] = (short)hh;
      l8[j] = (short)ll;
    }
    long dst = ((long)(slot * 16 + nt) * 4 + ks) * 512 + l * 8;
    *(bf16x8*)(w1ph + dst) = h8;
    *(bf16x8*)(w1pl + dst) = l8;
  } else {                              // W2 frags: 10 slots x 4 nt x 8 ks
    int fid = bid - 640;
    int slot = fid >> 5, rem = fid & 31;
    int nt = rem >> 3, ks = rem & 7;
    int grp = slot / 5, h = slot % 5;
    bool isE = h < 2;
    if (!isE && nt >= 2) return;        // R heads: only 32 out cols
    int NC = isE ? E_ : R_;
    const float* src = isE ? ((grp ? ieW2 : ueW2) + h * (HID_ * E_))
                           : ((grp ? irW2 : urW2) + (h - 2) * (HID_ * R_));
    int kk = ks * 32 + (l >> 4) * 8;
    int n = nt * 16 + (l & 15);
#pragma unroll
    for (int j = 0; j < 8; ++j) {
      unsigned short hh, ll;
      split1(src[(long)(kk + j) * NC + n], hh, ll);
      h8[j] = (short)hh;
      l8[j] = (short)ll;
    }
    long dst = ((long)(slot * 4 + nt) * 8 + ks) * 512 + l * 8;
    *(bf16x8*)(w2ph + dst) = h8;
    *(bf16x8*)(w2pl + dst) = l8;
  }
}

// ---------------------------------------------------------------------------
// K2 v11: MFMA MLP with bf16x3 split (hi*hi + hi*lo + lo*hi).
// Block = 256 thr (4 waves), 32-row tile, 1 head; grid 650.
// Layer 1: each wave owns a 64-col quarter: 2 Mt x 4 Nt x 4 Ks x 3 = 96 MFMA.
//   A-frags: lane reads X[rowbase+mt*16+(l&15)][ks*32+(l>>4)*8 ..+7] direct
//   from global (2 float4), splits to hi/lo.  B-frags: 1 b128 from prepped W.
// C layout (m89-verified): col = lane&15, row = (lane>>4)*4 + reg.
// bias+tanh on C frags -> split -> Hhi/Hlo LDS [32][264] u16 (row-major,
// pad 264 to stagger banks).  One __syncthreads (cross-wave H exchange).
// Layer 2: E: wave = 16-col tile, 2 Mt x 8 Ks x 3 = 48 MFMA.
//          R: wave = (mt = w>>1, nt = w&1), 8 Ks x 3 = 24 MFMA.
//   A-frags re-read from H LDS with the SAME k-convention (cancellation).
// ---------------------------------------------------------------------------
__global__ __launch_bounds__(256) void k_mlp(
    const float* __restrict__ X,
    const unsigned short* __restrict__ w1ph, const unsigned short* __restrict__ w1pl,
    const unsigned short* __restrict__ w2ph, const unsigned short* __restrict__ w2pl,
    const float* __restrict__ ueb1, const float* __restrict__ urb1,
    const float* __restrict__ ieb1, const float* __restrict__ irb1,
    const float* __restrict__ ueb2, const float* __restrict__ urb2,
    const float* __restrict__ ieb2, const float* __restrict__ irb2,
    float* __restrict__ oE0, float* __restrict__ oE1,
    float* __restrict__ oR0, float* __restrict__ oR1, float* __restrict__ oR2) {
  __shared__ unsigned short Hhi[32][264];
  __shared__ unsigned short Hlo[32][264];

  int h = blockIdx.x % 5;
  int tile = blockIdx.x / 5;
  int rowbase = tile * 32;
  int grp = (rowbase >= 4096) ? 1 : 0;
  bool isE = (h < 2);
  int slot = grp * 5 + h;
  const float* b1 = isE ? ((grp ? ieb1 : ueb1) + h * HID_)
                        : ((grp ? irb1 : urb1) + (h - 2) * HID_);
  const float* b2 = isE ? ((grp ? ieb2 : ueb2) + h * E_)
                        : ((grp ? irb2 : urb2) + (h - 2) * R_);
  float* out = (h == 0) ? oE0 : (h == 1) ? oE1 : (h == 2) ? oR0 : (h == 3) ? oR1 : oR2;

  int tid = threadIdx.x;
  int w = tid >> 6;        // wave -> N-quarter (layer 1)
  int l = tid & 63;
  int lr = l & 15;         // A-row / B-col / C-col index
  int lk = l >> 4;         // k-group

  // ---- layer 1 ----
  f32x4 acc[2][4];
#pragma unroll
  for (int mt = 0; mt < 2; ++mt)
#pragma unroll
    for (int ntl = 0; ntl < 4; ++ntl) acc[mt][ntl] = (f32x4){0.f, 0.f, 0.f, 0.f};

  const unsigned short* w1hS = w1ph + (long)slot * 32768 + l * 8;
  const unsigned short* w1lS = w1pl + (long)slot * 32768 + l * 8;

#pragma unroll
  for (int ks = 0; ks < 4; ++ks) {
    bf16x8 ah[2], al[2];
#pragma unroll
    for (int mt = 0; mt < 2; ++mt) {
      const float* xp = X + (long)(rowbase + mt * 16 + lr) * SYM_ + ks * 32 + lk * 8;
      float4 x0 = *(const float4*)xp;
      float4 x1 = *(const float4*)(xp + 4);
      split8(x0, x1, ah[mt], al[mt]);
    }
#pragma unroll
    for (int ntl = 0; ntl < 4; ++ntl) {
      int nt = 4 * w + ntl;
      long fo = ((long)nt * 4 + ks) * 512;
      bf16x8 bh = *(const bf16x8*)(w1hS + fo);
      bf16x8 bl = *(const bf16x8*)(w1lS + fo);
#pragma unroll
      for (int mt = 0; mt < 2; ++mt) {
        acc[mt][ntl] = MFMA16(ah[mt], bh, acc[mt][ntl], 0, 0, 0);
        acc[mt][ntl] = MFMA16(ah[mt], bl, acc[mt][ntl], 0, 0, 0);
        acc[mt][ntl] = MFMA16(al[mt], bh, acc[mt][ntl], 0, 0, 0);
      }
    }
  }

  // bias + tanh -> split -> H LDS
#pragma unroll
  for (int ntl = 0; ntl < 4; ++ntl) {
    int col = (4 * w + ntl) * 16 + lr;
    float bb = b1[col];
#pragma unroll
    for (int mt = 0; mt < 2; ++mt)
#pragma unroll
      for (int reg = 0; reg < 4; ++reg) {
        float t = fast_tanh(acc[mt][ntl][reg] + bb);
        unsigned short hh, ll;
        split1(t, hh, ll);
        int row = mt * 16 + lk * 4 + reg;
        Hhi[row][col] = hh;
        Hlo[row][col] = ll;
      }
  }
  __syncthreads();

  // ---- layer 2 ----
  if (isE) {
    const unsigned short* w2hS = w2ph + (long)slot * 16384 + l * 8;
    const unsigned short* w2lS = w2pl + (long)slot * 16384 + l * 8;
    int nt2 = w;
    f32x4 acc2[2];
    acc2[0] = (f32x4){0.f, 0.f, 0.f, 0.f};
    acc2[1] = (f32x4){0.f, 0.f, 0.f, 0.f};
#pragma unroll
    for (int ks2 = 0; ks2 < 8; ++ks2) {
      long fo = ((long)nt2 * 8 + ks2) * 512;
      bf16x8 bh = *(const bf16x8*)(w2hS + fo);
      bf16x8 bl = *(const bf16x8*)(w2lS + fo);
#pragma unroll
      for (int mt = 0; mt < 2; ++mt) {
        int row = mt * 16 + lr, kh = ks2 * 32 + lk * 8;
        bf16x8 ah2 = *(const bf16x8*)&Hhi[row][kh];
        bf16x8 al2 = *(const bf16x8*)&Hlo[row][kh];
        acc2[mt] = MFMA16(ah2, bh, acc2[mt], 0, 0, 0);
        acc2[mt] = MFMA16(ah2, bl, acc2[mt], 0, 0, 0);
        acc2[mt] = MFMA16(al2, bh, acc2[mt], 0, 0, 0);
      }
    }
    int col2 = nt2 * 16 + lr;
    float bb2 = b2[col2];
#pragma unroll
    for (int mt = 0; mt < 2; ++mt)
#pragma unroll
      for (int reg = 0; reg < 4; ++reg)
        out[(long)(rowbase + mt * 16 + lk * 4 + reg) * E_ + col2] = acc2[mt][reg] + bb2;
  } else {
    const unsigned short* w2hS = w2ph + (long)slot * 16384 + l * 8;
    const unsigned short* w2lS = w2pl + (long)slot * 16384 + l * 8;
    int mt = w >> 1, nt2 = w & 1;
    f32x4 acc2 = (f32x4){0.f, 0.f, 0.f, 0.f};
#pragma unroll
    for (int ks2 = 0; ks2 < 8; ++ks2) {
      long fo = ((long)nt2 * 8 + ks2) * 512;
      bf16x8 bh = *(const bf16x8*)(w2hS + fo);
      bf16x8 bl = *(const bf16x8*)(w2lS + fo);
      int row = mt * 16 + lr, kh = ks2 * 32 + lk * 8;
      bf16x8 ah2 = *(const bf16x8*)&Hhi[row][kh];
      bf16x8 al2 = *(const bf16x8*)&Hlo[row][kh];
      acc2 = MFMA16(ah2, bh, acc2, 0, 0, 0);
      acc2 = MFMA16(ah2, bl, acc2, 0, 0, 0);
      acc2 = MFMA16(al2, bh, acc2, 0, 0, 0);
    }
    int col2 = nt2 * 16 + lr;
    float bb2 = b2[col2];
#pragma unroll
    for (int reg = 0; reg < 4; ++reg)
      out[(long)(rowbase + mt * 16 + lk * 4 + reg) * R_ + col2] = acc2[reg] + bb2;
  }
}

// ---------------------------------------------------------------------------
// K_gram v2 (unchanged)
// ---------------------------------------------------------------------------
__global__ __launch_bounds__(256) void k_gram(
    const float* __restrict__ e1, const float* __restrict__ e2,
    const float* __restrict__ r1, const float* __restrict__ r2,
    const float* __restrict__ r3, float* __restrict__ Wt) {
  int b = blockIdx.x / 9, m = blockIdx.x % 9;
  const float* sE = ((m < 6) ? e1 : e2) + (long)b * S_ * E_;
  const float* jE = ((m == 2 || m == 5 || m == 8) ? e2 : e1) + (long)b * S_ * E_;
  int sk = m / 3, jk = m % 3;
  const float* sR = ((sk == 0) ? r1 : (sk == 1) ? r2 : r3) + (long)b * S_ * R_;
  const float* jR = ((jk == 0) ? r1 : (jk == 1) ? r2 : r3) + (long)b * S_ * R_;

  __shared__ float Es[64][68], Ej[64][68], Rs[64][36], Rj[64][36];
  int tid = threadIdx.x;
  for (int i = tid; i < 1024; i += 256) {
    int row = i >> 4, c = i & 15;
    *(float4*)&Es[row][4 * c] = *(const float4*)(sE + row * 64 + 4 * c);
    *(float4*)&Ej[row][4 * c] = *(const float4*)(jE + row * 64 + 4 * c);
  }
  for (int i = tid; i < 512; i += 256) {
    int row = i >> 3, c = i & 7;
    *(float4*)&Rs[row][4 * c] = *(const float4*)(sR + row * 32 + 4 * c);
    *(float4*)&Rj[row][4 * c] = *(const float4*)(jR + row * 32 + 4 * c);
  }
  __syncthreads();

  int s0 = (tid & 15) * 4, j0 = (tid >> 4) * 4;
  float ed[4][4] = {}, rd[4][4] = {};
#pragma unroll 4
  for (int k = 0; k < 16; ++k) {
    float4 es[4], ej[4];
#pragma unroll
    for (int i = 0; i < 4; ++i) {
      es[i] = *(const float4*)&Es[s0 + i][4 * k];
      ej[i] = *(const float4*)&Ej[j0 + i][4 * k];
    }
#pragma unroll
    for (int i = 0; i < 4; ++i)
#pragma unroll
      for (int j = 0; j < 4; ++j)
        ed[i][j] = fmaf(es[i].x, ej[j].x, fmaf(es[i].y, ej[j].y,
                   fmaf(es[i].z, ej[j].z, fmaf(es[i].w, ej[j].w, ed[i][j]))));
  }
#pragma unroll 4
  for (int k = 0; k < 8; ++k) {
    float4 rs[4], rj[4];
#pragma unroll
    for (int i = 0; i < 4; ++i) {
      rs[i] = *(const float4*)&Rs[s0 + i][4 * k];
      rj[i] = *(const float4*)&Rj[j0 + i][4 * k];
    }
#pragma unroll
    for (int i = 0; i < 4; ++i)
#pragma unroll
      for (int j = 0; j < 4; ++j)
        rd[i][j] = fmaf(rs[i].x, rj[j].x, fmaf(rs[i].y, rj[j].y,
                   fmaf(rs[i].z, rj[j].z, fmaf(rs[i].w, rj[j].w, rd[i][j]))));
  }
  float* wout = Wt + (long)(b * 9 + m) * 4096;
#pragma unroll
  for (int jj = 0; jj < 4; ++jj) {
    float4 o4 = make_float4(ed[0][jj] * rd[0][jj], ed[1][jj] * rd[1][jj],
                            ed[2][jj] * rd[2][jj], ed[3][jj] * rd[3][jj]);
    *(float4*)(wout + (j0 + jj) * 64 + s0) = o4;
  }
}

// ---------------------------------------------------------------------------
// K_scan v6 (unchanged)
// ---------------------------------------------------------------------------
__global__ __launch_bounds__(256) void k_scan(
    const float* __restrict__ e1g, const float* __restrict__ e2g,
    const float* __restrict__ Wt, float4* __restrict__ acd) {
  __shared__ float WtL[9 * 512];
  int b = blockIdx.x & 63;
  int g = blockIdx.x >> 6;
  int tid = threadIdx.x;
  int wv = tid >> 6;
  int lane = tid & 63;
  int f0 = g * 8 + wv * 2;
  int f1 = f0 + 1;
  const float* Wb = Wt + (long)b * 9 * 4096;
  long eoff = ((long)b * 64 + lane) * 64;
  float e1x = e1g[eoff + f0], e1y = e1g[eoff + f1];
  float e2x = e2g[eoff + f0], e2y = e2g[eoff + f1];

  float pW0 = 0.f, pM0 = 0.f, pB0 = 0.f;
  float pW1 = 0.f, pM1 = 0.f, pB1 = 0.f;
  float ca0 = e2x, cc0 = 0.f, cd0 = e1x;
  float ca1 = e2y, cc1 = 0.f, cd1 = e1y;
  float ka0 = 0.f, kc0 = 0.f, kd0 = 0.f;
  float ka1 = 0.f, kc1 = 0.f, kd1 = 0.f;

  for (int jc = 0; jc < 8; ++jc) {
    __syncthreads();
    for (int i = tid; i < 1152; i += 256) {
      int m = i >> 7;
      int off = (i & 127) * 4;
      *(float4*)&WtL[m * 512 + off] = *(const float4*)(Wb + m * 4096 + jc * 512 + off);
    }
    __syncthreads();
#pragma unroll
    for (int jj = 0; jj < 8; ++jj) {
      int j = jc * 8 + jj;
      float wa = WtL[0 * 512 + jj * 64 + lane];
      float wc = WtL[1 * 512 + jj * 64 + lane];
      float wd = WtL[2 * 512 + jj * 64 + lane];
      float ma = WtL[3 * 512 + jj * 64 + lane];
      float mc = WtL[4 * 512 + jj * 64 + lane];
      float md = WtL[5 * 512 + jj * 64 + lane];
      float ba = WtL[6 * 512 + jj * 64 + lane];
      float bc = WtL[7 * 512 + jj * 64 + lane];
      float bd = WtL[8 * 512 + jj * 64 + lane];
      float aj0 = __int_as_float(__builtin_amdgcn_readlane(__float_as_int(ca0), j));
      float cj0 = __int_as_float(__builtin_amdgcn_readlane(__float_as_int(cc0), j));
      float dj0 = __int_as_float(__builtin_amdgcn_readlane(__float_as_int(cd0), j));
      float aj1 = __int_as_float(__builtin_amdgcn_readlane(__float_as_int(ca1), j));
      float cj1 = __int_as_float(__builtin_amdgcn_readlane(__float_as_int(cc1), j));
      float dj1 = __int_as_float(__builtin_amdgcn_readlane(__float_as_int(cd1), j));
      bool own = (lane == j);
      ka0 = own ? ca0 : ka0; kc0 = own ? cc0 : kc0; kd0 = own ? cd0 : kd0;
      ka1 = own ? ca1 : ka1; kc1 = own ? cc1 : kc1; kd1 = own ? cd1 : kd1;
      pW0 = fmaf(wa, aj0, pW0); pW0 = fmaf(wc, cj0, pW0); pW0 = fmaf(wd, dj0, pW0);
      pM0 = fmaf(ma, aj0, pM0); pM0 = fmaf(mc, cj0, pM0); pM0 = fmaf(md, dj0, pM0);
      pB0 = fmaf(ba, aj0, pB0); pB0 = fmaf(bc, cj0, pB0); pB0 = fmaf(bd, dj0, pB0);
      pW1 = fmaf(wa, aj1, pW1); pW1 = fmaf(wc, cj1, pW1); pW1 = fmaf(wd, dj1, pW1);
      pM1 = fmaf(ma, aj1, pM1); pM1 = fmaf(mc, cj1, pM1); pM1 = fmaf(md, dj1, pM1);
      pB1 = fmaf(ba, aj1, pB1); pB1 = fmaf(bc, cj1, pB1); pB1 = fmaf(bd, dj1, pB1);
      ca0 = e2x - pW0; cc0 = pW0 - pM0; cd0 = e1x - pB0;
      ca1 = e2y - pW1; cc1 = pW1 - pM1; cd1 = e1y - pB1;
    }
  }
  acd[eoff + f0] = make_float4(ka0, kc0, kd0, 0.f);
  acd[eoff + f1] = make_float4(ka1, kc1, kd1, 0.f);
}

// ---------------------------------------------------------------------------
// K_infer (unchanged)
// ---------------------------------------------------------------------------
__global__ __launch_bounds__(1024) void k_infer(
    const float4* __restrict__ acd,
    const float* __restrict__ e1, const float* __restrict__ e2,
    const float* __restrict__ r1, const float* __restrict__ r2,
    const float* __restrict__ r3,
    const float* __restrict__ qe1, const float* __restrict__ qr1,
    const float* __restrict__ qr2, const float* __restrict__ qr3,
    const float* __restrict__ lng, const float* __restrict__ lnb,
    float* __restrict__ isum) {
  int b = blockIdx.x, tid = threadIdx.x;
  __shared__ float hista[64 * 65], histc[64 * 65], histd[64 * 65];
  __shared__ float vlds[9 * 64];
  __shared__ float ivec[64];
  __shared__ float u1s[64], u2s[64];
  __shared__ float dsc[64];

  {
    const float4* ab = acd + (long)b * 4096;
    for (int idx = tid; idx < 4096; idx += 1024) {
      float4 hv = ab[idx];
      int j = idx >> 6, f = idx & 63;
      hista[j * 65 + f] = hv.x;
      histc[j * 65 + f] = hv.y;
      histd[j * 65 + f] = hv.z;
    }
  }
  if (tid < 576) {
    int pk = tid >> 6, j = tid & 63;
    int p = pk / 3, k = pk % 3;
    const float* rv = ((k == 0) ? r1 : (k == 1) ? r2 : r3) + ((long)b * 64 + j) * 32;
    const float* q = ((p == 0) ? qr1 : (p == 1) ? qr2 : qr3) + b * 32;
    float acc = 0.f;
#pragma unroll
    for (int t = 0; t < 8; ++t) {
      float4 rv4 = *(const float4*)(rv + 4 * t);
      float4 q4 = *(const float4*)(q + 4 * t);
      acc = fmaf(rv4.x, q4.x, fmaf(rv4.y, q4.y,
            fmaf(rv4.z, q4.z, fmaf(rv4.w, q4.w, acc))));
    }
    vlds[pk * 64 + j] = acc;
  }
  if (tid < 64) ivec[tid] = qe1[b * 64 + tid];
  __syncthreads();

  int f = tid >> 4, jsl = tid & 15;
  int dotd = tid >> 3, dt = tid & 7;
  int which = dotd >> 6, dj = dotd & 63;
  const float* erow = (which ? e2 : e1) + ((long)b * 64 + dj) * 64 + dt * 8;
  float isacc = 0.f;
  for (int p = 0; p < 3; ++p) {
    {
      float acc = 0.f;
#pragma unroll
      for (int t = 0; t < 8; ++t)
        acc = fmaf(erow[t], ivec[dt * 8 + t], acc);
      acc += __shfl_xor(acc, 1, 64);
      acc += __shfl_xor(acc, 2, 64);
      acc += __shfl_xor(acc, 4, 64);
      if (dt == 0) { if (which) u2s[dj] = acc; else u1s[dj] = acc; }
    }
    __syncthreads();
    float part = 0.f;
#pragma unroll
    for (int i = 0; i < 4; ++i) {
      int j = jsl * 4 + i;
      float ca = u1s[j] * vlds[(p * 3 + 0) * 64 + j];
      float cc = u1s[j] * vlds[(p * 3 + 1) * 64 + j];
      float cd = u2s[j] * vlds[(p * 3 + 2) * 64 + j];
      part = fmaf(ca, hista[j * 65 + f],
             fmaf(cc, histc[j * 65 + f],
             fmaf(cd, histd[j * 65 + f], part)));
    }
    part += __shfl_xor(part, 1, 64);
    part += __shfl_xor(part, 2, 64);
    part += __shfl_xor(part, 4, 64);
    part += __shfl_xor(part, 8, 64);
    if (jsl == 0) dsc[f] = part;
    __syncthreads();
    if (tid < 64) {
      float v = dsc[tid];
      float mu = v;
#pragma unroll
      for (int mm = 1; mm <= 32; mm <<= 1) mu += __shfl_xor(mu, mm, 64);
      mu *= (1.f / 64.f);
      float d = v - mu;
      float vr = d * d;
#pragma unroll
      for (int mm = 1; mm <= 32; mm <<= 1) vr += __shfl_xor(vr, mm, 64);
      vr *= (1.f / 64.f);
      float iv = d * (1.f / sqrtf(vr + 1e-5f)) * lng[p * 64 + tid] + lnb[p * 64 + tid];
      ivec[tid] = iv;
      isacc += iv;
    }
    __syncthreads();
  }
  if (tid < 64) isum[b * 64 + tid] = isacc;
}

// ---------------------------------------------------------------------------
// K5 (unchanged)
// ---------------------------------------------------------------------------
__global__ __launch_bounds__(256) void k_final(
    const float* __restrict__ isum, const float* __restrict__ Zm,
    float* __restrict__ out) {
  __shared__ float isT[64 * 68];
  int tid = threadIdx.x;
  for (int i = tid; i < 4096; i += 256) {
    int bb = i >> 6, e = i & 63;
    isT[e * 68 + bb] = isum[i];
  }
  __syncthreads();
  int tr = tid >> 4, tc = tid & 15;
  int v0 = blockIdx.x * 64 + tc * 4;
  float acc[4][4] = {};
#pragma unroll 2
  for (int e = 0; e < 64; ++e) {
    float4 a4 = *(const float4*)&isT[e * 68 + 4 * tr];
    float4 z4 = *(const float4*)(Zm + (long)e * V_ + v0);
    float as[4] = {a4.x, a4.y, a4.z, a4.w};
    float zs[4] = {z4.x, z4.y, z4.z, z4.w};
#pragma unroll
    for (int i = 0; i < 4; ++i)
#pragma unroll
      for (int j = 0; j < 4; ++j) acc[i][j] = fmaf(as[i], zs[j], acc[i][j]);
  }
#pragma unroll
  for (int i = 0; i < 4; ++i) {
    float4 o4 = make_float4(acc[i][0], acc[i][1], acc[i][2], acc[i][3]);
    *(float4*)(out + (long)(4 * tr + i) * V_ + v0) = o4;
  }
}

// ---------------------------------------------------------------------------
extern "C" void kernel_launch(void* const* d_in, const int* in_sizes, int n_in,
                              void* d_out, int out_size, void* d_ws, size_t ws_size,
                              hipStream_t stream) {
  const int* story = (const int*)d_in[0];
  const int* query = (const int*)d_in[1];
  const float* we = (const float*)d_in[2];
  const float* pe = (const float*)d_in[3];
  const float* ueW1 = (const float*)d_in[4];
  const float* ueb1 = (const float*)d_in[5];
  const float* ueW2 = (const float*)d_in[6];
  const float* ueb2 = (const float*)d_in[7];
  const float* urW1 = (const float*)d_in[8];
  const float* urb1 = (const float*)d_in[9];
  const float* urW2 = (const float*)d_in[10];
  const float* urb2 = (const float*)d_in[11];
  const float* ieW1 = (const float*)d_in[12];
  const float* ieb1 = (const float*)d_in[13];
  const float* ieW2 = (const float*)d_in[14];
  const float* ieb2 = (const float*)d_in[15];
  const float* irW1 = (const float*)d_in[16];
  const float* irb1 = (const float*)d_in[17];
  const float* irW2 = (const float*)d_in[18];
  const float* irb2 = (const float*)d_in[19];
  const float* lng = (const float*)d_in[20];
  const float* lnb = (const float*)d_in[21];
  const float* Zm = (const float*)d_in[22];

  float* ws = (float*)d_ws;
  float* X = ws;                        // 4160*128 = 532480
  float* e1 = X + 532480;               // 4160*64  = 266240
  float* e2 = e1 + 266240;              // 266240
  float* r1 = e2 + 266240;              // 4160*32  = 133120
  float* r2 = r1 + 133120;              // 133120
  float* r3 = r2 + 133120;              // 133120
  float* isum = r3 + 133120;            // 4096
  float* Wt = isum + 4096;              // 9*64*4096 = 2359296
  float4* acd = (float4*)(Wt + 2359296);  // 64*64*64 float4 = 4 MB
  float* qe1 = e1 + 4096 * 64;
  float* qr1 = r1 + 4096 * 32;
  float* qr2 = r2 + 4096 * 32;
  float* qr3 = r3 + 4096 * 32;
  float* outF = (float*)d_out;

  // Prepped weights ALIAS the Wt region (dead until k_gram runs; k_wprep and
  // k_mlp both complete before k_gram overwrites it).  Needs 983040 u16
  // = 1.92 MB << 9.4 MB.
  unsigned short* w1ph = (unsigned short*)Wt;
  unsigned short* w1pl = w1ph + 327680;   // 10*32768
  unsigned short* w2ph = w1pl + 327680;
  unsigned short* w2pl = w2ph + 163840;   // 10*16384

  k_embed<<<4160, 128, 0, stream>>>(story, query, we, pe, X);
  k_wprep<<<960, 64, 0, stream>>>(ueW1, urW1, ieW1, irW1, ueW2, urW2, ieW2, irW2,
                                  w1ph, w1pl, w2ph, w2pl);
  k_mlp<<<130 * 5, 256, 0, stream>>>(X, w1ph, w1pl, w2ph, w2pl,
                                     ueb1, urb1, ieb1, irb1,
                                     ueb2, urb2, ieb2, irb2,
                                     e1, e2, r1, r2, r3);
  k_gram<<<64 * 9, 256, 0, stream>>>(e1, e2, r1, r2, r3, Wt);
  k_scan<<<512, 256, 0, stream>>>(e1, e2, Wt, acd);
  k_infer<<<B_, 1024, 0, stream>>>(acd, e1, e2, r1, r2, r3, qe1, qr1, qr2, qr3,
                                   lng, lnb, isum);
  k_final<<<V_ / 64, 256, 0, stream>>>(isum, Zm, outF);
}

// Round 5
// 194.608 us; speedup vs baseline: 1.3123x; 1.0167x over previous
//
#include <hip/hip_runtime.h>
#include <math.h>

// Problem constants
#define B_   64
#define S_   64
#define W_   12
#define V_   32000
#define SYM_ 128
#define HID_ 256
#define E_   64
#define R_   32

typedef short bf16x8 __attribute__((ext_vector_type(8)));
typedef float f32x4 __attribute__((ext_vector_type(4)));
#define MFMA16 __builtin_amdgcn_mfma_f32_16x16x32_bf16

__device__ __forceinline__ float fast_tanh(float x) {
  float e = __expf(2.0f * x);
  return 1.0f - 2.0f * __builtin_amdgcn_rcpf(e + 1.0f);
}

__device__ __forceinline__ float bcastf(float v, int lane) {
  return __int_as_float(__builtin_amdgcn_readlane(__float_as_int(v), lane));
}

// fp32 -> bf16 hi (truncate) + bf16 lo (RNE of exact residual).
__device__ __forceinline__ void split1(float x, unsigned short& h, unsigned short& l) {
  unsigned u = __float_as_uint(x);
  h = (unsigned short)(u >> 16);
  float r = x - __uint_as_float(u & 0xFFFF0000u);
  unsigned v = __float_as_uint(r);
  l = (unsigned short)((v + 0x7FFFu + ((v >> 16) & 1u)) >> 16);
}

__device__ __forceinline__ void split8(const float4& a, const float4& b,
                                       bf16x8& h8, bf16x8& l8) {
  float xs[8] = {a.x, a.y, a.z, a.w, b.x, b.y, b.z, b.w};
#pragma unroll
  for (int j = 0; j < 8; ++j) {
    unsigned short hh, ll;
    split1(xs[j], hh, ll);
    h8[j] = (short)hh;
    l8[j] = (short)ll;
  }
}

// ---------------------------------------------------------------------------
// K_prep: fused k_embed (blocks 0..4159, 128 thr) + k_wprep (blocks 4160..5119,
// first 64 lanes).  Independent work; one dispatch saves a launch gap.
// ---------------------------------------------------------------------------
__global__ __launch_bounds__(128) void k_prep(
    const int* __restrict__ story, const int* __restrict__ query,
    const float* __restrict__ we, const float* __restrict__ pe,
    float* __restrict__ X,
    const float* __restrict__ ueW1, const float* __restrict__ urW1,
    const float* __restrict__ ieW1, const float* __restrict__ irW1,
    const float* __restrict__ ueW2, const float* __restrict__ urW2,
    const float* __restrict__ ieW2, const float* __restrict__ irW2,
    unsigned short* __restrict__ w1ph, unsigned short* __restrict__ w1pl,
    unsigned short* __restrict__ w2ph, unsigned short* __restrict__ w2pl) {
  if (blockIdx.x < 4160) {
    // ---- embed ----
    int row = blockIdx.x;
    int e = threadIdx.x;
    const int* idx = (row < 4096) ? story + row * W_ : query + (row - 4096) * W_;
    float acc = 0.f;
#pragma unroll
    for (int w = 0; w < W_; ++w)
      acc = fmaf(we[(long)idx[w] * SYM_ + e], pe[w * SYM_ + e], acc);
    X[row * SYM_ + e] = acc;
    return;
  }
  // ---- wprep ----
  int l = threadIdx.x;
  if (l >= 64) return;
  int bid = blockIdx.x - 4160;
  bf16x8 h8, l8;
  if (bid < 640) {                      // W1 frags: 10 slots x 16 nt x 4 ks
    int slot = bid >> 6, rem = bid & 63;
    int nt = rem >> 2, ks = rem & 3;
    int grp = slot / 5, h = slot % 5;
    const float* src = (h < 2) ? ((grp ? ieW1 : ueW1) + h * (SYM_ * HID_))
                               : ((grp ? irW1 : urW1) + (h - 2) * (SYM_ * HID_));
    int kk = ks * 32 + (l >> 4) * 8;
    int n = nt * 16 + (l & 15);
#pragma unroll
    for (int j = 0; j < 8; ++j) {
      unsigned short hh, ll;
      split1(src[(long)(kk + j) * HID_ + n], hh, ll);
      h8[j] = (short)hh;
      l8[j] = (short)ll;
    }
    long dst = ((long)(slot * 16 + nt) * 4 + ks) * 512 + l * 8;
    *(bf16x8*)(w1ph + dst) = h8;
    *(bf16x8*)(w1pl + dst) = l8;
  } else {                              // W2 frags: 10 slots x 4 nt x 8 ks
    int fid = bid - 640;
    int slot = fid >> 5, rem = fid & 31;
    int nt = rem >> 3, ks = rem & 7;
    int grp = slot / 5, h = slot % 5;
    bool isE = h < 2;
    if (!isE && nt >= 2) return;        // R heads: only 32 out cols
    int NC = isE ? E_ : R_;
    const float* src = isE ? ((grp ? ieW2 : ueW2) + h * (HID_ * E_))
                           : ((grp ? irW2 : urW2) + (h - 2) * (HID_ * R_));
    int kk = ks * 32 + (l >> 4) * 8;
    int n = nt * 16 + (l & 15);
#pragma unroll
    for (int j = 0; j < 8; ++j) {
      unsigned short hh, ll;
      split1(src[(long)(kk + j) * NC + n], hh, ll);
      h8[j] = (short)hh;
      l8[j] = (short)ll;
    }
    long dst = ((long)(slot * 4 + nt) * 8 + ks) * 512 + l * 8;
    *(bf16x8*)(w2ph + dst) = h8;
    *(bf16x8*)(w2pl + dst) = l8;
  }
}

// ---------------------------------------------------------------------------
// K2 v11: MFMA MLP with bf16x3 split (unchanged from R4)
// ---------------------------------------------------------------------------
__global__ __launch_bounds__(256) void k_mlp(
    const float* __restrict__ X,
    const unsigned short* __restrict__ w1ph, const unsigned short* __restrict__ w1pl,
    const unsigned short* __restrict__ w2ph, const unsigned short* __restrict__ w2pl,
    const float* __restrict__ ueb1, const float* __restrict__ urb1,
    const float* __restrict__ ieb1, const float* __restrict__ irb1,
    const float* __restrict__ ueb2, const float* __restrict__ urb2,
    const float* __restrict__ ieb2, const float* __restrict__ irb2,
    float* __restrict__ oE0, float* __restrict__ oE1,
    float* __restrict__ oR0, float* __restrict__ oR1, float* __restrict__ oR2) {
  __shared__ unsigned short Hhi[32][264];
  __shared__ unsigned short Hlo[32][264];

  int h = blockIdx.x % 5;
  int tile = blockIdx.x / 5;
  int rowbase = tile * 32;
  int grp = (rowbase >= 4096) ? 1 : 0;
  bool isE = (h < 2);
  int slot = grp * 5 + h;
  const float* b1 = isE ? ((grp ? ieb1 : ueb1) + h * HID_)
                        : ((grp ? irb1 : urb1) + (h - 2) * HID_);
  const float* b2 = isE ? ((grp ? ieb2 : ueb2) + h * E_)
                        : ((grp ? irb2 : urb2) + (h - 2) * R_);
  float* out = (h == 0) ? oE0 : (h == 1) ? oE1 : (h == 2) ? oR0 : (h == 3) ? oR1 : oR2;

  int tid = threadIdx.x;
  int w = tid >> 6;
  int l = tid & 63;
  int lr = l & 15;
  int lk = l >> 4;

  // ---- layer 1 ----
  f32x4 acc[2][4];
#pragma unroll
  for (int mt = 0; mt < 2; ++mt)
#pragma unroll
    for (int ntl = 0; ntl < 4; ++ntl) acc[mt][ntl] = (f32x4){0.f, 0.f, 0.f, 0.f};

  const unsigned short* w1hS = w1ph + (long)slot * 32768 + l * 8;
  const unsigned short* w1lS = w1pl + (long)slot * 32768 + l * 8;

#pragma unroll
  for (int ks = 0; ks < 4; ++ks) {
    bf16x8 ah[2], al[2];
#pragma unroll
    for (int mt = 0; mt < 2; ++mt) {
      const float* xp = X + (long)(rowbase + mt * 16 + lr) * SYM_ + ks * 32 + lk * 8;
      float4 x0 = *(const float4*)xp;
      float4 x1 = *(const float4*)(xp + 4);
      split8(x0, x1, ah[mt], al[mt]);
    }
#pragma unroll
    for (int ntl = 0; ntl < 4; ++ntl) {
      int nt = 4 * w + ntl;
      long fo = ((long)nt * 4 + ks) * 512;
      bf16x8 bh = *(const bf16x8*)(w1hS + fo);
      bf16x8 bl = *(const bf16x8*)(w1lS + fo);
#pragma unroll
      for (int mt = 0; mt < 2; ++mt) {
        acc[mt][ntl] = MFMA16(ah[mt], bh, acc[mt][ntl], 0, 0, 0);
        acc[mt][ntl] = MFMA16(ah[mt], bl, acc[mt][ntl], 0, 0, 0);
        acc[mt][ntl] = MFMA16(al[mt], bh, acc[mt][ntl], 0, 0, 0);
      }
    }
  }

  // bias + tanh -> split -> H LDS
#pragma unroll
  for (int ntl = 0; ntl < 4; ++ntl) {
    int col = (4 * w + ntl) * 16 + lr;
    float bb = b1[col];
#pragma unroll
    for (int mt = 0; mt < 2; ++mt)
#pragma unroll
      for (int reg = 0; reg < 4; ++reg) {
        float t = fast_tanh(acc[mt][ntl][reg] + bb);
        unsigned short hh, ll;
        split1(t, hh, ll);
        int row = mt * 16 + lk * 4 + reg;
        Hhi[row][col] = hh;
        Hlo[row][col] = ll;
      }
  }
  __syncthreads();

  // ---- layer 2 ----
  if (isE) {
    const unsigned short* w2hS = w2ph + (long)slot * 16384 + l * 8;
    const unsigned short* w2lS = w2pl + (long)slot * 16384 + l * 8;
    int nt2 = w;
    f32x4 acc2[2];
    acc2[0] = (f32x4){0.f, 0.f, 0.f, 0.f};
    acc2[1] = (f32x4){0.f, 0.f, 0.f, 0.f};
#pragma unroll
    for (int ks2 = 0; ks2 < 8; ++ks2) {
      long fo = ((long)nt2 * 8 + ks2) * 512;
      bf16x8 bh = *(const bf16x8*)(w2hS + fo);
      bf16x8 bl = *(const bf16x8*)(w2lS + fo);
#pragma unroll
      for (int mt = 0; mt < 2; ++mt) {
        int row = mt * 16 + lr, kh = ks2 * 32 + lk * 8;
        bf16x8 ah2 = *(const bf16x8*)&Hhi[row][kh];
        bf16x8 al2 = *(const bf16x8*)&Hlo[row][kh];
        acc2[mt] = MFMA16(ah2, bh, acc2[mt], 0, 0, 0);
        acc2[mt] = MFMA16(ah2, bl, acc2[mt], 0, 0, 0);
        acc2[mt] = MFMA16(al2, bh, acc2[mt], 0, 0, 0);
      }
    }
    int col2 = nt2 * 16 + lr;
    float bb2 = b2[col2];
#pragma unroll
    for (int mt = 0; mt < 2; ++mt)
#pragma unroll
      for (int reg = 0; reg < 4; ++reg)
        out[(long)(rowbase + mt * 16 + lk * 4 + reg) * E_ + col2] = acc2[mt][reg] + bb2;
  } else {
    const unsigned short* w2hS = w2ph + (long)slot * 16384 + l * 8;
    const unsigned short* w2lS = w2pl + (long)slot * 16384 + l * 8;
    int mt = w >> 1, nt2 = w & 1;
    f32x4 acc2 = (f32x4){0.f, 0.f, 0.f, 0.f};
#pragma unroll
    for (int ks2 = 0; ks2 < 8; ++ks2) {
      long fo = ((long)nt2 * 8 + ks2) * 512;
      bf16x8 bh = *(const bf16x8*)(w2hS + fo);
      bf16x8 bl = *(const bf16x8*)(w2lS + fo);
      int row = mt * 16 + lr, kh = ks2 * 32 + lk * 8;
      bf16x8 ah2 = *(const bf16x8*)&Hhi[row][kh];
      bf16x8 al2 = *(const bf16x8*)&Hlo[row][kh];
      acc2 = MFMA16(ah2, bh, acc2, 0, 0, 0);
      acc2 = MFMA16(ah2, bl, acc2, 0, 0, 0);
      acc2 = MFMA16(al2, bh, acc2, 0, 0, 0);
    }
    int col2 = nt2 * 16 + lr;
    float bb2 = b2[col2];
#pragma unroll
    for (int reg = 0; reg < 4; ++reg)
      out[(long)(rowbase + mt * 16 + lk * 4 + reg) * R_ + col2] = acc2[reg] + bb2;
  }
}

// ---------------------------------------------------------------------------
// K_gram v2 (unchanged)
// ---------------------------------------------------------------------------
__global__ __launch_bounds__(256) void k_gram(
    const float* __restrict__ e1, const float* __restrict__ e2,
    const float* __restrict__ r1, const float* __restrict__ r2,
    const float* __restrict__ r3, float* __restrict__ Wt) {
  int b = blockIdx.x / 9, m = blockIdx.x % 9;
  const float* sE = ((m < 6) ? e1 : e2) + (long)b * S_ * E_;
  const float* jE = ((m == 2 || m == 5 || m == 8) ? e2 : e1) + (long)b * S_ * E_;
  int sk = m / 3, jk = m % 3;
  const float* sR = ((sk == 0) ? r1 : (sk == 1) ? r2 : r3) + (long)b * S_ * R_;
  const float* jR = ((jk == 0) ? r1 : (jk == 1) ? r2 : r3) + (long)b * S_ * R_;

  __shared__ float Es[64][68], Ej[64][68], Rs[64][36], Rj[64][36];
  int tid = threadIdx.x;
  for (int i = tid; i < 1024; i += 256) {
    int row = i >> 4, c = i & 15;
    *(float4*)&Es[row][4 * c] = *(const float4*)(sE + row * 64 + 4 * c);
    *(float4*)&Ej[row][4 * c] = *(const float4*)(jE + row * 64 + 4 * c);
  }
  for (int i = tid; i < 512; i += 256) {
    int row = i >> 3, c = i & 7;
    *(float4*)&Rs[row][4 * c] = *(const float4*)(sR + row * 32 + 4 * c);
    *(float4*)&Rj[row][4 * c] = *(const float4*)(jR + row * 32 + 4 * c);
  }
  __syncthreads();

  int s0 = (tid & 15) * 4, j0 = (tid >> 4) * 4;
  float ed[4][4] = {}, rd[4][4] = {};
#pragma unroll 4
  for (int k = 0; k < 16; ++k) {
    float4 es[4], ej[4];
#pragma unroll
    for (int i = 0; i < 4; ++i) {
      es[i] = *(const float4*)&Es[s0 + i][4 * k];
      ej[i] = *(const float4*)&Ej[j0 + i][4 * k];
    }
#pragma unroll
    for (int i = 0; i < 4; ++i)
#pragma unroll
      for (int j = 0; j < 4; ++j)
        ed[i][j] = fmaf(es[i].x, ej[j].x, fmaf(es[i].y, ej[j].y,
                   fmaf(es[i].z, ej[j].z, fmaf(es[i].w, ej[j].w, ed[i][j]))));
  }
#pragma unroll 4
  for (int k = 0; k < 8; ++k) {
    float4 rs[4], rj[4];
#pragma unroll
    for (int i = 0; i < 4; ++i) {
      rs[i] = *(const float4*)&Rs[s0 + i][4 * k];
      rj[i] = *(const float4*)&Rj[j0 + i][4 * k];
    }
#pragma unroll
    for (int i = 0; i < 4; ++i)
#pragma unroll
      for (int j = 0; j < 4; ++j)
        rd[i][j] = fmaf(rs[i].x, rj[j].x, fmaf(rs[i].y, rj[j].y,
                   fmaf(rs[i].z, rj[j].z, fmaf(rs[i].w, rj[j].w, rd[i][j]))));
  }
  float* wout = Wt + (long)(b * 9 + m) * 4096;
#pragma unroll
  for (int jj = 0; jj < 4; ++jj) {
    float4 o4 = make_float4(ed[0][jj] * rd[0][jj], ed[1][jj] * rd[1][jj],
                            ed[2][jj] * rd[2][jj], ed[3][jj] * rd[3][jj]);
    *(float4*)(wout + (j0 + jj) * 64 + s0) = o4;
  }
}

// ---------------------------------------------------------------------------
// K_scan v7: 4 f per lane (Wt reads amortize over 2x FMAs) + packed LDS
// WtL[jj][s][12] so the 9 per-lane Wt values are 2x ds_read_b128 + 1x b32
// (lane stride 48B: lanes 0-7 cover all 32 banks -> conflict-free).
// Grid 256 (64 b x 4 quarters), 256 thr; staging redundancy 8x -> 4x.
// FMA order per f identical to v6 -> bit-exact.
// ---------------------------------------------------------------------------
__global__ __launch_bounds__(256) void k_scan(
    const float* __restrict__ e1g, const float* __restrict__ e2g,
    const float* __restrict__ Wt, float4* __restrict__ acd) {
  __shared__ float WtL[8][64][12];
  int b = blockIdx.x & 63;
  int gq = blockIdx.x >> 6;        // 0..3
  int tid = threadIdx.x;
  int wv = tid >> 6;
  int lane = tid & 63;             // = s
  int fbase = gq * 16 + wv * 4;    // lane handles f = fbase..fbase+3
  const float* Wb = Wt + (long)b * 9 * 4096;
  long eoff = ((long)b * 64 + lane) * 64;
  float4 e1v = *(const float4*)(e1g + eoff + fbase);
  float4 e2v = *(const float4*)(e2g + eoff + fbase);
  float e1a[4] = {e1v.x, e1v.y, e1v.z, e1v.w};
  float e2a[4] = {e2v.x, e2v.y, e2v.z, e2v.w};

  float pW[4], pM[4], pB[4], ca[4], cc[4], cd[4], ka[4], kc[4], kd[4];
#pragma unroll
  for (int f = 0; f < 4; ++f) {
    pW[f] = pM[f] = pB[f] = 0.f;
    ka[f] = kc[f] = kd[f] = 0.f;
    ca[f] = e2a[f]; cc[f] = 0.f; cd[f] = e1a[f];
  }

  for (int jc = 0; jc < 8; ++jc) {
    __syncthreads();
    // stage: wave wv fills jj = 2wv, 2wv+1; coalesced global reads,
    // packed b128 LDS writes
#pragma unroll
    for (int t = 0; t < 2; ++t) {
      int jj = wv * 2 + t;
      const float* src = Wb + jc * 512 + jj * 64 + lane;
      float v[9];
#pragma unroll
      for (int m = 0; m < 9; ++m) v[m] = src[m * 4096];
      float* dst = &WtL[jj][lane][0];
      *(float4*)dst = make_float4(v[0], v[1], v[2], v[3]);
      *(float4*)(dst + 4) = make_float4(v[4], v[5], v[6], v[7]);
      dst[8] = v[8];
    }
    __syncthreads();
#pragma unroll
    for (int jj = 0; jj < 8; ++jj) {
      int j = jc * 8 + jj;
      const float* wrow = &WtL[jj][lane][0];
      float4 w03 = *(const float4*)wrow;
      float4 w47 = *(const float4*)(wrow + 4);
      float bd = wrow[8];
      float wa = w03.x, wc = w03.y, wd = w03.z;
      float ma = w03.w, mc = w47.x, md = w47.y;
      float ba = w47.z, bc = w47.w;
      bool own = (lane == j);
#pragma unroll
      for (int f = 0; f < 4; ++f) {
        float aj = bcastf(ca[f], j);
        float cj = bcastf(cc[f], j);
        float dj = bcastf(cd[f], j);
        ka[f] = own ? ca[f] : ka[f];
        kc[f] = own ? cc[f] : kc[f];
        kd[f] = own ? cd[f] : kd[f];
        pW[f] = fmaf(wa, aj, pW[f]); pW[f] = fmaf(wc, cj, pW[f]); pW[f] = fmaf(wd, dj, pW[f]);
        pM[f] = fmaf(ma, aj, pM[f]); pM[f] = fmaf(mc, cj, pM[f]); pM[f] = fmaf(md, dj, pM[f]);
        pB[f] = fmaf(ba, aj, pB[f]); pB[f] = fmaf(bc, cj, pB[f]); pB[f] = fmaf(bd, dj, pB[f]);
        ca[f] = e2a[f] - pW[f]; cc[f] = pW[f] - pM[f]; cd[f] = e1a[f] - pB[f];
      }
    }
  }
#pragma unroll
  for (int f = 0; f < 4; ++f)
    acd[eoff + fbase + f] = make_float4(ka[f], kc[f], kd[f], 0.f);
}

// ---------------------------------------------------------------------------
// K_infer (unchanged)
// ---------------------------------------------------------------------------
__global__ __launch_bounds__(1024) void k_infer(
    const float4* __restrict__ acd,
    const float* __restrict__ e1, const float* __restrict__ e2,
    const float* __restrict__ r1, const float* __restrict__ r2,
    const float* __restrict__ r3,
    const float* __restrict__ qe1, const float* __restrict__ qr1,
    const float* __restrict__ qr2, const float* __restrict__ qr3,
    const float* __restrict__ lng, const float* __restrict__ lnb,
    float* __restrict__ isum) {
  int b = blockIdx.x, tid = threadIdx.x;
  __shared__ float hista[64 * 65], histc[64 * 65], histd[64 * 65];
  __shared__ float vlds[9 * 64];
  __shared__ float ivec[64];
  __shared__ float u1s[64], u2s[64];
  __shared__ float dsc[64];

  {
    const float4* ab = acd + (long)b * 4096;
    for (int idx = tid; idx < 4096; idx += 1024) {
      float4 hv = ab[idx];
      int j = idx >> 6, f = idx & 63;
      hista[j * 65 + f] = hv.x;
      histc[j * 65 + f] = hv.y;
      histd[j * 65 + f] = hv.z;
    }
  }
  if (tid < 576) {
    int pk = tid >> 6, j = tid & 63;
    int p = pk / 3, k = pk % 3;
    const float* rv = ((k == 0) ? r1 : (k == 1) ? r2 : r3) + ((long)b * 64 + j) * 32;
    const float* q = ((p == 0) ? qr1 : (p == 1) ? qr2 : qr3) + b * 32;
    float acc = 0.f;
#pragma unroll
    for (int t = 0; t < 8; ++t) {
      float4 rv4 = *(const float4*)(rv + 4 * t);
      float4 q4 = *(const float4*)(q + 4 * t);
      acc = fmaf(rv4.x, q4.x, fmaf(rv4.y, q4.y,
            fmaf(rv4.z, q4.z, fmaf(rv4.w, q4.w, acc))));
    }
    vlds[pk * 64 + j] = acc;
  }
  if (tid < 64) ivec[tid] = qe1[b * 64 + tid];
  __syncthreads();

  int f = tid >> 4, jsl = tid & 15;
  int dotd = tid >> 3, dt = tid & 7;
  int which = dotd >> 6, dj = dotd & 63;
  const float* erow = (which ? e2 : e1) + ((long)b * 64 + dj) * 64 + dt * 8;
  float isacc = 0.f;
  for (int p = 0; p < 3; ++p) {
    {
      float acc = 0.f;
#pragma unroll
      for (int t = 0; t < 8; ++t)
        acc = fmaf(erow[t], ivec[dt * 8 + t], acc);
      acc += __shfl_xor(acc, 1, 64);
      acc += __shfl_xor(acc, 2, 64);
      acc += __shfl_xor(acc, 4, 64);
      if (dt == 0) { if (which) u2s[dj] = acc; else u1s[dj] = acc; }
    }
    __syncthreads();
    float part = 0.f;
#pragma unroll
    for (int i = 0; i < 4; ++i) {
      int j = jsl * 4 + i;
      float ca = u1s[j] * vlds[(p * 3 + 0) * 64 + j];
      float cc = u1s[j] * vlds[(p * 3 + 1) * 64 + j];
      float cd = u2s[j] * vlds[(p * 3 + 2) * 64 + j];
      part = fmaf(ca, hista[j * 65 + f],
             fmaf(cc, histc[j * 65 + f],
             fmaf(cd, histd[j * 65 + f], part)));
    }
    part += __shfl_xor(part, 1, 64);
    part += __shfl_xor(part, 2, 64);
    part += __shfl_xor(part, 4, 64);
    part += __shfl_xor(part, 8, 64);
    if (jsl == 0) dsc[f] = part;
    __syncthreads();
    if (tid < 64) {
      float v = dsc[tid];
      float mu = v;
#pragma unroll
      for (int mm = 1; mm <= 32; mm <<= 1) mu += __shfl_xor(mu, mm, 64);
      mu *= (1.f / 64.f);
      float d = v - mu;
      float vr = d * d;
#pragma unroll
      for (int mm = 1; mm <= 32; mm <<= 1) vr += __shfl_xor(vr, mm, 64);
      vr *= (1.f / 64.f);
      float iv = d * (1.f / sqrtf(vr + 1e-5f)) * lng[p * 64 + tid] + lnb[p * 64 + tid];
      ivec[tid] = iv;
      isacc += iv;
    }
    __syncthreads();
  }
  if (tid < 64) isum[b * 64 + tid] = isacc;
}

// ---------------------------------------------------------------------------
// K5 (unchanged)
// ---------------------------------------------------------------------------
__global__ __launch_bounds__(256) void k_final(
    const float* __restrict__ isum, const float* __restrict__ Zm,
    float* __restrict__ out) {
  __shared__ float isT[64 * 68];
  int tid = threadIdx.x;
  for (int i = tid; i < 4096; i += 256) {
    int bb = i >> 6, e = i & 63;
    isT[e * 68 + bb] = isum[i];
  }
  __syncthreads();
  int tr = tid >> 4, tc = tid & 15;
  int v0 = blockIdx.x * 64 + tc * 4;
  float acc[4][4] = {};
#pragma unroll 2
  for (int e = 0; e < 64; ++e) {
    float4 a4 = *(const float4*)&isT[e * 68 + 4 * tr];
    float4 z4 = *(const float4*)(Zm + (long)e * V_ + v0);
    float as[4] = {a4.x, a4.y, a4.z, a4.w};
    float zs[4] = {z4.x, z4.y, z4.z, z4.w};
#pragma unroll
    for (int i = 0; i < 4; ++i)
#pragma unroll
      for (int j = 0; j < 4; ++j) acc[i][j] = fmaf(as[i], zs[j], acc[i][j]);
  }
#pragma unroll
  for (int i = 0; i < 4; ++i) {
    float4 o4 = make_float4(acc[i][0], acc[i][1], acc[i][2], acc[i][3]);
    *(float4*)(out + (long)(4 * tr + i) * V_ + v0) = o4;
  }
}

// ---------------------------------------------------------------------------
extern "C" void kernel_launch(void* const* d_in, const int* in_sizes, int n_in,
                              void* d_out, int out_size, void* d_ws, size_t ws_size,
                              hipStream_t stream) {
  const int* story = (const int*)d_in[0];
  const int* query = (const int*)d_in[1];
  const float* we = (const float*)d_in[2];
  const float* pe = (const float*)d_in[3];
  const float* ueW1 = (const float*)d_in[4];
  const float* ueb1 = (const float*)d_in[5];
  const float* ueW2 = (const float*)d_in[6];
  const float* ueb2 = (const float*)d_in[7];
  const float* urW1 = (const float*)d_in[8];
  const float* urb1 = (const float*)d_in[9];
  const float* urW2 = (const float*)d_in[10];
  const float* urb2 = (const float*)d_in[11];
  const float* ieW1 = (const float*)d_in[12];
  const float* ieb1 = (const float*)d_in[13];
  const float* ieW2 = (const float*)d_in[14];
  const float* ieb2 = (const float*)d_in[15];
  const float* irW1 = (const float*)d_in[16];
  const float* irb1 = (const float*)d_in[17];
  const float* irW2 = (const float*)d_in[18];
  const float* irb2 = (const float*)d_in[19];
  const float* lng = (const float*)d_in[20];
  const float* lnb = (const float*)d_in[21];
  const float* Zm = (const float*)d_in[22];

  float* ws = (float*)d_ws;
  float* X = ws;                        // 4160*128 = 532480
  float* e1 = X + 532480;               // 4160*64  = 266240
  float* e2 = e1 + 266240;              // 266240
  float* r1 = e2 + 266240;              // 4160*32  = 133120
  float* r2 = r1 + 133120;              // 133120
  float* r3 = r2 + 133120;              // 133120
  float* isum = r3 + 133120;            // 4096
  float* Wt = isum + 4096;              // 9*64*4096 = 2359296
  float4* acd = (float4*)(Wt + 2359296);  // 64*64*64 float4 = 4 MB
  float* qe1 = e1 + 4096 * 64;
  float* qr1 = r1 + 4096 * 32;
  float* qr2 = r2 + 4096 * 32;
  float* qr3 = r3 + 4096 * 32;
  float* outF = (float*)d_out;

  // Prepped weights alias the Wt region (dead until k_gram runs).
  unsigned short* w1ph = (unsigned short*)Wt;
  unsigned short* w1pl = w1ph + 327680;   // 10*32768
  unsigned short* w2ph = w1pl + 327680;
  unsigned short* w2pl = w2ph + 163840;   // 10*16384

  k_prep<<<4160 + 960, 128, 0, stream>>>(story, query, we, pe, X,
                                         ueW1, urW1, ieW1, irW1,
                                         ueW2, urW2, ieW2, irW2,
                                         w1ph, w1pl, w2ph, w2pl);
  k_mlp<<<130 * 5, 256, 0, stream>>>(X, w1ph, w1pl, w2ph, w2pl,
                                     ueb1, urb1, ieb1, irb1,
                                     ueb2, urb2, ieb2, irb2,
                                     e1, e2, r1, r2, r3);
  k_gram<<<64 * 9, 256, 0, stream>>>(e1, e2, r1, r2, r3, Wt);
  k_scan<<<256, 256, 0, stream>>>(e1, e2, Wt, acd);
  k_infer<<<B_, 1024, 0, stream>>>(acd, e1, e2, r1, r2, r3, qe1, qr1, qr2, qr3,
                                   lng, lnb, isum);
  k_final<<<V_ / 64, 256, 0, stream>>>(isum, Zm, outF);
}